// Round 6
// baseline (1609.823 us; speedup 1.0000x reference)
//
#include <hip/hip_runtime.h>
#include <cmath>

typedef _Float16 f16_t;                                         // IEEE fp16
typedef __attribute__((ext_vector_type(8))) short short8;       // MFMA A/B frag (bit container)
typedef __attribute__((ext_vector_type(8))) _Float16 half8;     // MFMA f16 frag
typedef __attribute__((ext_vector_type(4))) float f32x4;        // MFMA C/D frag
typedef _Float16 h2v __attribute__((ext_vector_type(2)));       // packed f16 pair
typedef _Float16 h8 __attribute__((ext_vector_type(8)));        // 16B f16 vector
typedef float f2 __attribute__((ext_vector_type(2)));           // packed f32 pair

#define NI_N 32768
#define NV_N 131072
#define E_VV 1048576
#define E_VI 524288
#define E_IV 524288
#define NT_N (NV_N+NV_N+NI_N)          // 294912 concatenated nodes (vv|iv|vi)
#define ET_N (E_VV+E_IV+E_VI)          // 2097152 concatenated edges
#define SC_WIN 4                        // scatter windows
#define LOG2E 1.4426950408889634f
#define CHV 192                         // row-chunks per var panel (colres)
#define CHI 64                          // row-chunks per ins panel
#define CHQ 256                         // row-chunks per qkv panel
#define EPAD 68                         // LDS transpose row stride (floats) - bank-conflict-free

__device__ __forceinline__ float gelu_f(float x){ return 0.5f*x*(1.0f+erff(x*0.7071067811865476f)); }

// split f32 into hi/lo f16 (hi+lo carries ~22 bits of mantissa)
__device__ __forceinline__ void splitf16(float v, short& hi, short& lo){
  f16_t h=(f16_t)v;
  hi=__builtin_bit_cast(short,h);
  f16_t l=(f16_t)(v-(float)h);
  lo=__builtin_bit_cast(short,l);
}
__device__ __forceinline__ f32x4 mfma16(short8 a, short8 b, f32x4 c){
  return __builtin_amdgcn_mfma_f32_16x16x32_f16(__builtin_bit_cast(half8,a),__builtin_bit_cast(half8,b),c,0,0,0);
}
__device__ __forceinline__ float fexp2(float x){
#if __has_builtin(__builtin_amdgcn_exp2f)
  return __builtin_amdgcn_exp2f(x);
#else
  return exp2f(x);
#endif
}
__device__ __forceinline__ float ldval(const float* p){ return *p; }
__device__ __forceinline__ float ldval(const f16_t* p){ return (float)*p; }
__device__ __forceinline__ void stval(float* p,float v){ *p=v; }
__device__ __forceinline__ void stval(f16_t* p,float v){ *p=(f16_t)v; }

// ---------------- fused CSR build over 3 concatenated edge types ----------------
__global__ __launch_bounds__(256) void k_hist3(const int* __restrict__ dvv,const int* __restrict__ div_,
    const int* __restrict__ dvi,int* __restrict__ cnt){
  int i=blockIdx.x*256+threadIdx.x;
  if(i<E_VV) atomicAdd(&cnt[dvv[i]],1);
  else if(i<E_VV+E_IV) atomicAdd(&cnt[NV_N+div_[i-E_VV]],1);
  else atomicAdd(&cnt[2*NV_N+dvi[i-E_VV-E_IV]],1);
}
__global__ __launch_bounds__(512) void k_scan1(const int* __restrict__ cnt,int N,int* __restrict__ rp,int* __restrict__ bsum){
  __shared__ int sh[512];
  int i=blockIdx.x*512+threadIdx.x;
  int v=(i<N)?cnt[i]:0;
  sh[threadIdx.x]=v; __syncthreads();
  for(int off=1;off<512;off<<=1){
    int t=(threadIdx.x>=(unsigned)off)?sh[threadIdx.x-off]:0; __syncthreads();
    sh[threadIdx.x]+=t; __syncthreads();
  }
  if(i<N) rp[i]=sh[threadIdx.x]-v;
  if(threadIdx.x==511) bsum[blockIdx.x]=sh[511];
}
__global__ __launch_bounds__(1024) void k_scan2(const int* __restrict__ bsum,int* __restrict__ boff,int nb){
  __shared__ int sh[1024];
  int t=threadIdx.x;
  int v=(t<nb)?bsum[t]:0;
  sh[t]=v; __syncthreads();
  for(int off=1;off<1024;off<<=1){
    int x=(t>=(unsigned)off)?sh[t-off]:0; __syncthreads();
    sh[t]+=x; __syncthreads();
  }
  if(t<nb) boff[t]=sh[t]-v;
  if(t==1023) boff[nb]=sh[1023];
}
__global__ __launch_bounds__(512) void k_scan3(int* __restrict__ rp,const int* __restrict__ boff,int* __restrict__ cur,int N,int nb){
  int i=blockIdx.x*512+threadIdx.x;
  if(i<N){ int v=rp[i]+boff[i>>9]; rp[i]=v; cur[i]=v; }
  if(i==0) rp[N]=boff[nb];
}
// scatter stores PRE-SCALED source row offsets (src*stride) so the edge kernel does no mul
__global__ __launch_bounds__(256) void k_scatter3w(const int* __restrict__ svv,const int* __restrict__ dvv,
    const int* __restrict__ siv,const int* __restrict__ div_,
    const int* __restrict__ svi,const int* __restrict__ dvi,
    int* __restrict__ cur,int* __restrict__ esrc,int dlo,int dhi){
  int i=blockIdx.x*256+threadIdx.x;
  int d,s;
  if(i<E_VV){ d=dvv[i]; if(d<dlo||d>=dhi) return; s=svv[i]*320; }
  else if(i<E_VV+E_IV){ int j=i-E_VV; d=NV_N+div_[j]; if(d<dlo||d>=dhi) return; s=siv[j]*192; }
  else { int j=i-E_VV-E_IV; d=2*NV_N+dvi[j]; if(d<dlo||d>=dhi) return; s=svi[j]*320; }
  int p=atomicAdd(&cur[d],1); esrc[p]=s;
}

// initial cast: f32 inputs -> f16 x buffers
__global__ __launch_bounds__(256) void k_castx(const float* __restrict__ xi_in,const float* __restrict__ xv_in,
    f16_t* __restrict__ xi,f16_t* __restrict__ xv){
  int i=blockIdx.x*256+threadIdx.x;
  if(i<NI_N*64) xi[i]=(f16_t)xi_in[i];
  else { int j=i-NI_N*64; xv[j]=(f16_t)xv_in[j]; }
}

// ---------------- weight folding for ALL 6 layers in one launch ----------------
// Contiguous block layout: q(64) | k(64) | v(64) [| k2 | v2] so the edge kernel
// loads per-head 16B k-rows and v-rows. q columns scaled by LOG2E for exp2 softmax.
struct FoldArgs{
  const float *Wk_i,*Wq_i,*Wv_i,*bk_i,*bq_i,*bv_i;
  const float *Wk_v,*Wq_v,*Wv_v,*bk_v,*bq_v,*bv_v;
  const float *arel_vv,*mrel_vv,*prel_vv,*arel_vi,*mrel_vi,*prel_vi,*arel_iv,*mrel_iv,*prel_iv;
  const float *Wa_i,*Wa_v;
  short *fwh_var,*fwl_var,*fwh_ins,*fwl_ins,*wah_i,*wal_i,*wah_v,*wal_v;
  float *fwb_var,*fwb_ins;
};
__global__ __launch_bounds__(256) void k_fold6(FoldArgs fa){
  int gid=blockIdx.x*256+threadIdx.x;
  if(gid>=6*640*64) return;
  int l=gid/(640*64);
  int rem=gid-l*640*64;
  int r=rem>>6, c=rem&63;
  if(r>=512){
    int ro=r&63;
    const float* W=(r<576)?fa.Wa_i:fa.Wa_v;
    short *sh=((r<576)?fa.wah_i:fa.wah_v)+l*4096, *sl=((r<576)?fa.wal_i:fa.wal_v)+l*4096;
    short h,lo; splitf16(W[l*4096+ro*64+c],h,lo);
    sh[ro*64+c]=h; sl[ro*64+c]=lo;
    return;
  }
  const float *W,*B,*rel=nullptr,*prl=nullptr;
  short *sh,*sl; float *fwb; int orow; bool isq=false;
  if(r<320){
    sh=fa.fwh_var+l*320*64; sl=fa.fwl_var+l*320*64; fwb=fa.fwb_var+l*320; orow=r;
    if(r<64){ W=fa.Wq_v; B=fa.bq_v; isq=true; }
    else if(r<128){ W=fa.Wk_v; B=fa.bk_v; rel=fa.arel_vv; prl=fa.prel_vv; }
    else if(r<192){ W=fa.Wv_v; B=fa.bv_v; rel=fa.mrel_vv; }
    else if(r<256){ W=fa.Wk_v; B=fa.bk_v; rel=fa.arel_vi; prl=fa.prel_vi; }
    else         { W=fa.Wv_v; B=fa.bv_v; rel=fa.mrel_vi; }
  }else{
    int rr=r-320; sh=fa.fwh_ins+l*192*64; sl=fa.fwl_ins+l*192*64; fwb=fa.fwb_ins+l*192; orow=rr;
    if(rr<64){ W=fa.Wq_i; B=fa.bq_i; isq=true; }
    else if(rr<128){ W=fa.Wk_i; B=fa.bk_i; rel=fa.arel_iv; prl=fa.prel_iv; }
    else           { W=fa.Wv_i; B=fa.bv_i; rel=fa.mrel_iv; }
  }
  int d=orow&63;
  float val,bval;
  if(!rel){
    val=W[l*4096+d*64+c]; bval=B[l*64+d];
  }else{
    int h=d>>3, e=d&7;
    float s=prl?prl[l*8+h]*0.3535533905932738f:1.0f;
    float acc=0.f,bacc=0.f;
    #pragma unroll
    for(int dd=0;dd<8;dd++){
      float rv=rel[l*512+h*64+dd*8+e];
      acc += W[l*4096+(h*8+dd)*64+c]*rv;
      bacc+= B[l*64+h*8+dd]*rv;
    }
    val=acc*s; bval=bacc*s;
  }
  if(isq){ val*=LOG2E; bval*=LOG2E; }
  short h2q,lo2; splitf16(val,h2q,lo2);
  sh[orow*64+c]=h2q; sl[orow*64+c]=lo2;
  if(c==0) fwb[orow]=bval;
}

__global__ __launch_bounds__(256) void k_split2(const float* __restrict__ W,int n,short* __restrict__ hi,short* __restrict__ lo){
  int i=blockIdx.x*256+threadIdx.x;
  if(i<n){ short h,l2; splitf16(W[i],h,l2); hi[i]=h; lo[i]=l2; }
}

// ---------------- column-resident GEMM: B frags live in registers, block grid-strides rows ----------------
__device__ __forceinline__ void colres_body(const f16_t* __restrict__ A,int nrb,
    const short* __restrict__ Bh,const short* __restrict__ Bl,
    const float* __restrict__ bias,f16_t* __restrict__ out,int octot,int ocol0,
    int c,int CH,int wave,int lane,int m,int quad,f16_t (*rep)[72])
{
  short8 bhi[4][2], blo[4][2]; float bb[4];
  #pragma unroll
  for(int ot=0;ot<4;ot++){
    size_t o=(size_t)(ocol0+ot*16+m)*64+quad*8;
    bhi[ot][0]=*(const short8*)(Bh+o);    bhi[ot][1]=*(const short8*)(Bh+o+32);
    blo[ot][0]=*(const short8*)(Bl+o);    blo[ot][1]=*(const short8*)(Bl+o+32);
    bb[ot]=bias[ocol0+ot*16+m];
  }
  int rr0=lane>>3, seg=lane&7;
  for(int rb=c;rb<nrb;rb+=CH){
    int row0=rb*64+wave*16;
    const f16_t* ap=A+(size_t)(row0+m)*64+quad*8;
    short8 a0=*(const short8*)(const void*)ap;
    short8 a1=*(const short8*)(const void*)(ap+32);
    f32x4 acc[4];
    #pragma unroll
    for(int ot=0;ot<4;ot++){ f32x4 t={bb[ot],bb[ot],bb[ot],bb[ot]}; acc[ot]=t; }
    #pragma unroll
    for(int ot=0;ot<4;ot++){
      acc[ot]=mfma16(a0,blo[ot][0],acc[ot]);
      acc[ot]=mfma16(a0,bhi[ot][0],acc[ot]);
      acc[ot]=mfma16(a1,blo[ot][1],acc[ot]);
      acc[ot]=mfma16(a1,bhi[ot][1],acc[ot]);
    }
    #pragma unroll
    for(int ot=0;ot<4;ot++)
      #pragma unroll
      for(int r=0;r<4;r++)
        rep[quad*4+r][ot*16+m]=(f16_t)acc[ot][r];
    #pragma unroll
    for(int it=0;it<2;it++){
      int rr=it*8+rr0;
      h8 vals=*(const h8*)&rep[rr][seg*8];
      *(h8*)(out+(size_t)(row0+rr)*octot+ocol0+seg*8)=vals;
    }
  }
}

// fused feature GEMM: blocks [0,5*CHV) var panels, rest ins panels
__global__ __launch_bounds__(256) void k_colres_feat(const f16_t* __restrict__ Av,const f16_t* __restrict__ Ai,
    const short* __restrict__ Bvh,const short* __restrict__ Bvl,const float* __restrict__ biasv,
    const short* __restrict__ Bih,const short* __restrict__ Bil,const float* __restrict__ biasi,
    f16_t* __restrict__ outv,f16_t* __restrict__ outi)
{
  __shared__ f16_t rep[4][16][72];
  const int wave=threadIdx.x>>6, lane=threadIdx.x&63;
  const int m=lane&15, quad=lane>>4;
  int bx=blockIdx.x;
  if(bx<5*CHV){
    int pan=bx/CHV, c=bx%CHV;
    colres_body(Av,NV_N/64,Bvh,Bvl,biasv,outv,320,pan*64,c,CHV,wave,lane,m,quad,rep[wave]);
  }else{
    bx-=5*CHV;
    int pan=bx/CHI, c=bx%CHI;
    colres_body(Ai,NI_N/64,Bih,Bil,biasi,outi,192,pan*64,c,CHI,wave,lane,m,quad,rep[wave]);
  }
}

// generic single-input column-resident GEMM (used for JK qkv)
__global__ __launch_bounds__(256) void k_colres1(const f16_t* __restrict__ A,int nrb,
    const short* __restrict__ Bh,const short* __restrict__ Bl,
    const float* __restrict__ bias,f16_t* __restrict__ out,int octot,int CH)
{
  __shared__ f16_t rep[4][16][72];
  const int wave=threadIdx.x>>6, lane=threadIdx.x&63;
  const int m=lane&15, quad=lane>>4;
  int pan=blockIdx.x/CH, c=blockIdx.x%CH;
  colres_body(A,nrb,Bh,Bl,bias,out,octot,pan*64,c,CH,wave,lane,m,quad,rep[wave]);
}

// ---------------- legacy GEMM body (float A path for osum @ Wo) ----------------
template<typename AT, typename OT>
__device__ __forceinline__ void gemm_body(const AT* __restrict__ A,int row0,
    const short* __restrict__ Bh,const short* __restrict__ Bl,
    const float* __restrict__ bias,float bias_scale,
    OT* __restrict__ out,int octot,int ocol0,int npanels,int m,int quad,int lane,
    f16_t (*rep)[72])
{
  const AT* ap=A+(size_t)(row0+m)*64+quad*8;
  constexpr bool AF16 = (sizeof(AT)==2);
  short8 ahi[2], alo[2];
  if constexpr(AF16){
    #pragma unroll
    for(int kf=0;kf<2;kf++) ahi[kf]=*(const short8*)(const void*)(ap+kf*32);
  }else{
    #pragma unroll
    for(int kf=0;kf<2;kf++){
      short8 th,tl;
      #pragma unroll
      for(int j=0;j<8;j++){ short h,l2; splitf16(ldval(&ap[kf*32+j]),h,l2); th[j]=h; tl[j]=l2; }
      ahi[kf]=th; alo[kf]=tl;
    }
  }
  for(int pan=0;pan<npanels;pan++){
    int colbase=pan*64;
    short8 bhi[4][2], blo[4][2];
    #pragma unroll
    for(int ot=0;ot<4;ot++){
      size_t o=(size_t)(colbase+ot*16+m)*64+quad*8;
      #pragma unroll
      for(int kf=0;kf<2;kf++){
        bhi[ot][kf]=*(const short8*)(Bh+o+kf*32);
        blo[ot][kf]=*(const short8*)(Bl+o+kf*32);
      }
    }
    f32x4 acc[4];
    #pragma unroll
    for(int ot=0;ot<4;ot++){
      float bv=bias[colbase+ot*16+m]*bias_scale;
      acc[ot][0]=bv; acc[ot][1]=bv; acc[ot][2]=bv; acc[ot][3]=bv;
    }
    #pragma unroll
    for(int ot=0;ot<4;ot++){
      #pragma unroll
      for(int kf=0;kf<2;kf++){
        if constexpr(!AF16) acc[ot]=mfma16(alo[kf],bhi[ot][kf],acc[ot]);
        acc[ot]=mfma16(ahi[kf],blo[ot][kf],acc[ot]);
        acc[ot]=mfma16(ahi[kf],bhi[ot][kf],acc[ot]);
      }
    }
    if constexpr(sizeof(OT)==2){
      #pragma unroll
      for(int ot=0;ot<4;ot++)
        #pragma unroll
        for(int r=0;r<4;r++)
          rep[quad*4+r][ot*16+m]=(f16_t)acc[ot][r];
      #pragma unroll
      for(int it=0;it<2;it++){
        int rr=it*8+(lane>>3), seg=lane&7;
        h8 vals=*(const h8*)&rep[rr][seg*8];
        *(h8*)(out+(size_t)(row0+rr)*octot+ocol0+colbase+seg*8)=vals;
      }
    }else{
      #pragma unroll
      for(int ot=0;ot<4;ot++){
        int col=ocol0+colbase+ot*16+m;
        #pragma unroll
        for(int r=0;r<4;r++){
          int row=row0+quad*4+r;
          stval(&out[(size_t)row*octot+col],acc[ot][r]);
        }
      }
    }
  }
}

template<typename AT, typename OT>
__global__ __launch_bounds__(256) void k_gemm64p(const AT* __restrict__ A,int N,
    const short* __restrict__ Bh,const short* __restrict__ Bl,
    const float* __restrict__ bias,float bias_scale,
    OT* __restrict__ out,int octot,int ocol0,int npanels)
{
  __shared__ f16_t rep[4][16][72];
  const int wave=threadIdx.x>>6, lane=threadIdx.x&63;
  const int m=lane&15, quad=lane>>4;
  const int row0=blockIdx.x*64+wave*16;
  if(row0>=N) return;
  gemm_body<AT,OT>(A,row0,Bh,Bl,bias,bias_scale,out,octot,ocol0,npanels,m,quad,lane,rep[wave]);
}

// ---------------- fused per-layer update (instr blocks then var blocks), x/agg f16, LDS-repacked I/O ----------------
__global__ __launch_bounds__(256) void k_update2(const f16_t* __restrict__ agg_i,const f16_t* __restrict__ agg_v,
    const short* __restrict__ wah_i,const short* __restrict__ wal_i,
    const short* __restrict__ wah_v,const short* __restrict__ wal_v,
    const float* __restrict__ ba_i,const float* __restrict__ ba_v,
    const float* __restrict__ skip_i,const float* __restrict__ skip_v,
    f16_t* __restrict__ x_i,f16_t* __restrict__ x_v,
    f16_t* __restrict__ outs,int nbi)
{
  __shared__ f16_t rep[4][16][72];
  const int wave=threadIdx.x>>6, lane=threadIdx.x&63;
  const int m=lane&15, quad=lane>>4;
  const bool isI=(int)blockIdx.x<nbi;
  const int row0=(isI?blockIdx.x:(blockIdx.x-nbi))*64+wave*16;
  const f16_t* agg=isI?agg_i:agg_v;
  const short* Wah=isI?wah_i:wah_v;
  const short* Wal=isI?wal_i:wal_v;
  const float* ba=isI?ba_i:ba_v;
  const float* skip=isI?skip_i:skip_v;
  f16_t* x=isI?x_i:x_v;
  f16_t* oo=isI?outs:nullptr;
  f16_t (*R)[72]=rep[wave];
  short8 bhi[4][2], blo[4][2];
  #pragma unroll
  for(int ot=0;ot<4;ot++){
    size_t o=(size_t)(ot*16+m)*64+quad*8;
    #pragma unroll
    for(int kf=0;kf<2;kf++){
      bhi[ot][kf]=*(const short8*)(Wah+o+kf*32);
      blo[ot][kf]=*(const short8*)(Wal+o+kf*32);
    }
  }
  const f16_t* ap=agg+(size_t)(row0+m)*64+quad*8;
  short8 ahi[2], alo[2];
  #pragma unroll
  for(int kf=0;kf<2;kf++){
    short8 th,tl;
    #pragma unroll
    for(int j=0;j<8;j++){ short h,l2; splitf16(gelu_f((float)ap[kf*32+j]),h,l2); th[j]=h; tl[j]=l2; }
    ahi[kf]=th; alo[kf]=tl;
  }
  // stage x rows into LDS (wide loads)
  int rr0=lane>>3, seg=lane&7;
  h8 x0=*(const h8*)(x+(size_t)(row0+rr0)*64+seg*8);
  h8 x1=*(const h8*)(x+(size_t)(row0+8+rr0)*64+seg*8);
  *(h8*)&R[rr0][seg*8]=x0;
  *(h8*)&R[8+rr0][seg*8]=x1;
  f32x4 acc[4];
  #pragma unroll
  for(int ot=0;ot<4;ot++){
    float bv=ba[ot*16+m];
    acc[ot][0]=bv; acc[ot][1]=bv; acc[ot][2]=bv; acc[ot][3]=bv;
  }
  #pragma unroll
  for(int ot=0;ot<4;ot++){
    #pragma unroll
    for(int kf=0;kf<2;kf++){
      acc[ot]=mfma16(alo[kf],bhi[ot][kf],acc[ot]);
      acc[ot]=mfma16(ahi[kf],blo[ot][kf],acc[ot]);
      acc[ot]=mfma16(ahi[kf],bhi[ot][kf],acc[ot]);
    }
  }
  float s=1.0f/(1.0f+__expf(-skip[0]));
  #pragma unroll
  for(int ot=0;ot<4;ot++){
    int col=ot*16+m;
    #pragma unroll
    for(int r=0;r<4;r++){
      int row=quad*4+r;
      float xn=s*acc[ot][r]+(1.0f-s)*(float)R[row][col];
      R[row][col]=(f16_t)xn;
    }
  }
  h8 o0=*(const h8*)&R[rr0][seg*8];
  h8 o1=*(const h8*)&R[8+rr0][seg*8];
  *(h8*)(x+(size_t)(row0+rr0)*64+seg*8)=o0;
  *(h8*)(x+(size_t)(row0+8+rr0)*64+seg*8)=o1;
  if(oo){
    *(h8*)(oo+(size_t)(row0+rr0)*64+seg*8)=o0;
    *(h8*)(oo+(size_t)(row0+8+rr0)*64+seg*8)=o1;
  }
}

// ---------------- edge attention v3: lane=(e_slot,head), 16-slot bodies, dual-direction overlap ----------------
// esrc holds PRE-SCALED row offsets. Layout q|k|v blocks; voff-koff == 64 elements (128B imm offset).
// q pre-scaled by LOG2E -> exp2 softmax.
struct ELoad { h8 ka,va,kb,vb; };
struct EState { float m, ls; f2 A0,A1,A2,A3; };

__device__ __forceinline__ void einit(EState& S){
  S.m=-1e30f; S.ls=0.f;
  f2 z={0.f,0.f};
  S.A0=z; S.A1=z; S.A2=z; S.A3=z;
}

// issue loads for 16 edge slots (2 per lane): es gather then k/v rows (v via +128B imm)
__device__ __forceinline__ ELoad eload16(const int* __restrict__ es,int i,int e,
    int e_slot,const f16_t* __restrict__ sfh)
{
  int em1=e-1;
  int ia=i+e_slot, ib=ia+8;
  int ca=ia<em1?ia:em1;
  int cb=ib<em1?ib:em1;
  int oa=es[ca], ob=es[cb];
  const f16_t* pa=sfh+(unsigned)oa;
  const f16_t* pb=sfh+(unsigned)ob;
  ELoad L;
  L.ka=*(const h8*)pa;
  L.va=*(const h8*)(pa+64);
  L.kb=*(const h8*)pb;
  L.vb=*(const h8*)(pb+64);
  return L;
}

__device__ __forceinline__ float dot8(h8 k,h2v q0,h2v q1,h2v q2,h2v q3){
#if __has_builtin(__builtin_amdgcn_fdot2)
  float p=__builtin_amdgcn_fdot2((h2v){k[0],k[1]},q0,0.f,false);
  p=__builtin_amdgcn_fdot2((h2v){k[2],k[3]},q1,p,false);
  p=__builtin_amdgcn_fdot2((h2v){k[4],k[5]},q2,p,false);
  p=__builtin_amdgcn_fdot2((h2v){k[6],k[7]},q3,p,false);
  return p;
#else
  return (float)k[0]*(float)q0[0]+(float)k[1]*(float)q0[1]
        +(float)k[2]*(float)q1[0]+(float)k[3]*(float)q1[1]
        +(float)k[4]*(float)q2[0]+(float)k[5]*(float)q2[1]
        +(float)k[6]*(float)q3[0]+(float)k[7]*(float)q3[1];
#endif
}

// online-softmax update for 2 edges. Clamped (invalid) logits duplicate a real edge
// -> max stays correct; only w is zeroed.
__device__ __forceinline__ void ecompute16(const ELoad& L,int i,int e,int e_slot,
    h2v q0,h2v q1,h2v q2,h2v q3,EState& S)
{
  float pa=dot8(L.ka,q0,q1,q2,q3);
  float pb=dot8(L.kb,q0,q1,q2,q3);
  float mn=fmaxf(S.m,fmaxf(pa,pb));
  float sc=fexp2(S.m-mn);
  bool oka=(i+e_slot)<e, okb=(i+e_slot+8)<e;
  float wa=oka?fexp2(pa-mn):0.f;
  float wb=okb?fexp2(pb-mn):0.f;
  S.ls=fmaf(S.ls,sc,wa+wb);
  f2 SS={sc,sc}, WA={wa,wa}, WB={wb,wb};
  S.A0=S.A0*SS+WA*(f2){(float)L.va[0],(float)L.va[1]}+WB*(f2){(float)L.vb[0],(float)L.vb[1]};
  S.A1=S.A1*SS+WA*(f2){(float)L.va[2],(float)L.va[3]}+WB*(f2){(float)L.vb[2],(float)L.vb[3]};
  S.A2=S.A2*SS+WA*(f2){(float)L.va[4],(float)L.va[5]}+WB*(f2){(float)L.vb[4],(float)L.vb[5]};
  S.A3=S.A3*SS+WA*(f2){(float)L.va[6],(float)L.va[7]}+WB*(f2){(float)L.vb[6],(float)L.vb[7]};
  S.m=mn;
}

// cross-e_slot combine: leaves A pre-normalized (scaled by scl/ls_total) so results
// from multiple directions can be summed and transposed in ONE LDS pass.
__device__ __forceinline__ void efinish(EState& S){
  float mall=fmaxf(S.m,__shfl_xor(S.m,8));
  mall=fmaxf(mall,__shfl_xor(mall,16));
  mall=fmaxf(mall,__shfl_xor(mall,32));
  float scl=fexp2(S.m-mall);         // empty direction: exp2(0)=1, ls=0 -> A stays 0
  float ls=S.ls*scl;
  float lsall=ls+__shfl_xor(ls,8);
  lsall+=__shfl_xor(lsall,16);
  lsall+=__shfl_xor(lsall,32);
  float nrm=scl/(lsall+1e-16f);
  f2 N={nrm,nrm};
  S.A0*=N; S.A1*=N; S.A2*=N; S.A3*=N;
}

// fused edge kernel: blocks [0,nbv) var destinations (vv+iv overlapped), rest instr destinations (vi)
__global__ __launch_bounds__(256) void k_edge_all(const int* __restrict__ rp_all,const int* __restrict__ es,
    const f16_t* __restrict__ var_feat,const f16_t* __restrict__ ins_feat,
    f16_t* __restrict__ agg_v,f16_t* __restrict__ agg_i,int nbv)
{
  __shared__ float lds[4][8*EPAD];
  int wave=threadIdx.x>>6, lane=threadIdx.x&63;
  int e_slot=lane>>3, h=lane&7, hb=h*8;
  float* L=lds[wave];
  if((int)blockIdx.x<nbv){
    int n=blockIdx.x*4+wave;
    int b1=__builtin_amdgcn_readfirstlane(rp_all[n]);
    int e1=__builtin_amdgcn_readfirstlane(rp_all[n+1]);
    const int* rp2=rp_all+NV_N;
    int b2=__builtin_amdgcn_readfirstlane(rp2[n]);
    int e2=__builtin_amdgcn_readfirstlane(rp2[n+1]);
    h8 qv=*(const h8*)(var_feat+(size_t)n*320+hb);
    h2v q0={qv[0],qv[1]},q1={qv[2],qv[3]},q2={qv[4],qv[5]},q3={qv[6],qv[7]};
    const f16_t* sfh1=var_feat+64+hb;   // vv: koff=64, voff=128
    const f16_t* sfh2=ins_feat+64+hb;   // iv: koff=64, voff=128
    EState S1,S2; einit(S1); einit(S2);
    int i1=b1,i2=b2;
    bool a1=b1<e1, a2=b2<e2;
    ELoad L1,L2;
    if(a1) L1=eload16(es,i1,e1,e_slot,sfh1);   // both directions' loads in flight together
    if(a2) L2=eload16(es,i2,e2,e_slot,sfh2);
    while(a1||a2){
      if(a1){
        ecompute16(L1,i1,e1,e_slot,q0,q1,q2,q3,S1);
        i1+=16; a1=i1<e1;
        if(a1) L1=eload16(es,i1,e1,e_slot,sfh1);
      }
      if(a2){
        ecompute16(L2,i2,e2,e_slot,q0,q1,q2,q3,S2);
        i2+=16; a2=i2<e2;
        if(a2) L2=eload16(es,i2,e2,e_slot,sfh2);
      }
    }
    efinish(S1); efinish(S2);
    f2 W0=S1.A0+S2.A0, W1=S1.A1+S2.A1, W2=S1.A2+S2.A2, W3=S1.A3+S2.A3;
    float* wp=L+e_slot*EPAD+hb;
    *(f32x4*)wp=(f32x4){W0[0],W0[1],W1[0],W1[1]};
    *(f32x4*)(wp+4)=(f32x4){W2[0],W2[1],W3[0],W3[1]};
    __asm__ volatile("s_waitcnt lgkmcnt(0)" ::: "memory");
    float r=0.f;
    #pragma unroll
    for(int ee=0;ee<8;ee++) r+=L[ee*EPAD+lane];
    agg_v[(size_t)n*64+lane]=(f16_t)r;
  }else{
    int n=(blockIdx.x-nbv)*4+wave;
    const int* rp=rp_all+2*NV_N;
    int b=__builtin_amdgcn_readfirstlane(rp[n]);
    int e=__builtin_amdgcn_readfirstlane(rp[n+1]);
    h8 qv=*(const h8*)(ins_feat+(size_t)n*192+hb);
    h2v q0={qv[0],qv[1]},q1={qv[2],qv[3]},q2={qv[4],qv[5]},q3={qv[6],qv[7]};
    const f16_t* sfh=var_feat+192+hb;   // vi: koff=192, voff=256
    EState S; einit(S);
    int i=b; bool a=b<e;
    ELoad Ld;
    if(a) Ld=eload16(es,i,e,e_slot,sfh);
    while(a){
      ecompute16(Ld,i,e,e_slot,q0,q1,q2,q3,S);
      i+=16; a=i<e;
      if(a) Ld=eload16(es,i,e,e_slot,sfh);
    }
    efinish(S);
    float* wp=L+e_slot*EPAD+hb;
    *(f32x4*)wp=(f32x4){S.A0[0],S.A0[1],S.A1[0],S.A1[1]};
    *(f32x4*)(wp+4)=(f32x4){S.A2[0],S.A2[1],S.A3[0],S.A3[1]};
    __asm__ volatile("s_waitcnt lgkmcnt(0)" ::: "memory");
    float r=0.f;
    #pragma unroll
    for(int ee=0;ee<8;ee++) r+=L[ee*EPAD+lane];
    agg_i[(size_t)n*64+lane]=(f16_t)r;
  }
}

// ---------------- jumping-knowledge 5x5 attention, one wave per node
__global__ __launch_bounds__(256) void k_jk(const f16_t* __restrict__ qkv,float* __restrict__ osum,int n_nodes){
  int wave=threadIdx.x>>6, lane=threadIdx.x&63;
  int n=blockIdx.x*4+wave;
  if(n>=n_nodes) return;
  float q[5],k[5],v[5];
  #pragma unroll
  for(int s=0;s<5;s++){
    const f16_t* p=qkv+((size_t)s*n_nodes+n)*192;
    q[s]=(float)p[lane]; k[s]=(float)p[64+lane]; v[s]=(float)p[128+lane];
  }
  float sc[5][5];
  #pragma unroll
  for(int s=0;s<5;s++)
    #pragma unroll
    for(int t=0;t<5;t++){
      float x=q[s]*k[t];
      x+=__shfl_xor(x,1); x+=__shfl_xor(x,2); x+=__shfl_xor(x,4);
      sc[s][t]=x*0.3535533905932738f;
    }
  float os=0.f;
  #pragma unroll
  for(int s=0;s<5;s++){
    float m=sc[s][0];
    #pragma unroll
    for(int t=1;t<5;t++) m=fmaxf(m,sc[s][t]);
    float den=0.f, acc=0.f;
    #pragma unroll
    for(int t=0;t<5;t++){ float e=__expf(sc[s][t]-m); den+=e; acc+=e*v[t]; }
    os+=acc/den;
  }
  osum[(size_t)n*64+lane]=os;
}

// ---------------- MLP head ----------------
struct MlpArgs{ const float *w0,*b0,*w1,*b1,*w2,*b2,*w3,*b3,*w4,*b4,*w5,*b5; };
__global__ __launch_bounds__(256) void k_mlp(const float* __restrict__ in,MlpArgs ma,float* __restrict__ out,int N){
  __shared__ float sw0[2048],sb0[32],sw1[512],sb1[16],sw2[128],sb2[8],sw3[32],sb3[4],sw4[8],sb4[2],sw5[2],sb5[1];
  for(int i=threadIdx.x;i<2048;i+=256) sw0[i]=ma.w0[i];
  for(int i=threadIdx.x;i<512;i+=256)  sw1[i]=ma.w1[i];
  if(threadIdx.x<128) sw2[threadIdx.x]=ma.w2[threadIdx.x];
  if(threadIdx.x<32){ sb0[threadIdx.x]=ma.b0[threadIdx.x]; sw3[threadIdx.x]=ma.w3[threadIdx.x]; }
  if(threadIdx.x<16) sb1[threadIdx.x]=ma.b1[threadIdx.x];
  if(threadIdx.x<8){ sb2[threadIdx.x]=ma.b2[threadIdx.x]; sw4[threadIdx.x]=ma.w4[threadIdx.x]; }
  if(threadIdx.x<4) sb3[threadIdx.x]=ma.b3[threadIdx.x];
  if(threadIdx.x<2){ sb4[threadIdx.x]=ma.b4[threadIdx.x]; sw5[threadIdx.x]=ma.w5[threadIdx.x]; }
  if(threadIdx.x==0) sb5[0]=ma.b5[0];
  __syncthreads();
  int n=blockIdx.x*256+threadIdx.x;
  if(n>=N) return;
  float a[64];
  const f32x4* p4=(const f32x4*)(in+(size_t)n*64);
  #pragma unroll
  for(int j=0;j<16;j++){ f32x4 t=p4[j]; a[4*j]=t[0]; a[4*j+1]=t[1]; a[4*j+2]=t[2]; a[4*j+3]=t[3]; }
  float h1[32];
  #pragma unroll
  for(int o=0;o<32;o++){ float s=sb0[o];
    #pragma unroll
    for(int c=0;c<64;c++) s+=a[c]*sw0[o*64+c];
    h1[o]=gelu_f(s); }
  float h2q[16];
  #pragma unroll
  for(int o=0;o<16;o++){ float s=sb1[o];
    #pragma unroll
    for(int c=0;c<32;c++) s+=h1[c]*sw1[o*32+c];
    h2q[o]=gelu_f(s); }
  float h3[8];
  #pragma unroll
  for(int o=0;o<8;o++){ float s=sb2[o];
    #pragma unroll
    for(int c=0;c<16;c++) s+=h2q[c]*sw2[o*16+c];
    h3[o]=gelu_f(s); }
  float h4[4];
  #pragma unroll
  for(int o=0;o<4;o++){ float s=sb3[o];
    #pragma unroll
    for(int c=0;c<8;c++) s+=h3[c]*sw3[o*8+c];
    h4[o]=gelu_f(s); }
  float h5[2];
  #pragma unroll
  for(int o=0;o<2;o++){ float s=sb4[o];
    #pragma unroll
    for(int c=0;c<4;c++) s+=h4[c]*sw4[o*4+c];
    h5[o]=gelu_f(s); }
  float r=sb5[0]+h5[0]*sw5[0]+h5[1]*sw5[1];
  out[n]=r;
}

// ================= host launcher =================
extern "C" void kernel_launch(void* const* d_in,const int* in_sizes,int n_in,
                              void* d_out,int out_size,void* d_ws,size_t ws_size,
                              hipStream_t stream){
  (void)in_sizes;(void)n_in;(void)out_size;(void)ws_size;
  const float* x_instr=(const float*)d_in[0];
  const float* x_var  =(const float*)d_in[1];
  const float* ba_i=(const float*)d_in[9];
  const float* skip_i=(const float*)d_in[10];
  const float* ba_v=(const float*)d_in[18];
  const float* skip_v=(const float*)d_in[19];
  const float* Wqkv=(const float*)d_in[29];
  const float* bqkv=(const float*)d_in[30];
  const float* Wo=(const float*)d_in[31];
  const float* bo=(const float*)d_in[32];
  const int* src_vv=(const int*)d_in[45];
  const int* dst_vv=(const int*)d_in[46];
  const int* src_vi=(const int*)d_in[47];
  const int* dst_vi=(const int*)d_in[48];
  const int* src_iv=(const int*)d_in[49];
  const int* dst_iv=(const int*)d_in[50];

  char* w=(char*)d_ws;
  auto alloc=[&](size_t b)->char*{ char* p=w; w+=(b+255)&~(size_t)255; return p; };
  // ---- fused CSR arrays (~12 MB) ----
  int* rp_all=(int*)alloc((size_t)(NT_N+1)*4);
  int* cnt_all=(int*)alloc((size_t)NT_N*4);
  int* cur_all=(int*)alloc((size_t)NT_N*4);
  int* bsum =(int*)alloc(640*4);
  int* boff =(int*)alloc(640*4);
  int* esrc_all=(int*)alloc((size_t)ET_N*4);
  // ---- folded + pre-split weights for all 6 layers (~2.5 MB) ----
  short* fwh_var=(short*)alloc((size_t)6*320*64*2);
  short* fwl_var=(short*)alloc((size_t)6*320*64*2);
  float* fwb_var=(float*)alloc((size_t)6*320*4);
  short* fwh_ins=(short*)alloc((size_t)6*192*64*2);
  short* fwl_ins=(short*)alloc((size_t)6*192*64*2);
  float* fwb_ins=(float*)alloc((size_t)6*192*4);
  short* wah_i=(short*)alloc((size_t)6*64*64*2);
  short* wal_i=(short*)alloc((size_t)6*64*64*2);
  short* wah_v=(short*)alloc((size_t)6*64*64*2);
  short* wal_v=(short*)alloc((size_t)6*64*64*2);
  short* qkvh=(short*)alloc(192*64*2);
  short* qkvl=(short*)alloc(192*64*2);
  short* woh=(short*)alloc(64*64*2);
  short* wol=(short*)alloc(64*64*2);
  // ---- persistent across phases: outs (f16, 21 MB) ----
  f16_t* outs=(f16_t*)alloc((size_t)5*NI_N*64*2);
  // ---- arena (140 MB), phase-overlaid ----
  char* arena=alloc((size_t)146800640);
  f16_t*  xv      =(f16_t*)(arena);                                // 16,777,216 B
  f16_t*  xi      =(f16_t*)(arena+16777216);                       //  4,194,304 B
  f16_t*  var_feat=(f16_t*)(arena+20971520);                       // 83,886,080 B (stride 320: q | k_vv | v_vv | k_vi | v_vi)
  f16_t*  ins_feat=(f16_t*)(arena+104857600);                      // 12,582,912 B (stride 192: q | k | v)
  f16_t*  agg_v   =(f16_t*)(arena+117440512);                      // 16,777,216 B
  f16_t*  agg_i   =(f16_t*)(arena+134217728);                      //  4,194,304 B
  // JK phase overlays (xv/xi/var_feat dead by then):
  f16_t*  qkv    =(f16_t*)(arena);                                 // 62,914,560 B
  float*  osum   =(float*)(arena+67108864);                        //  8,388,608 B (inside dead var_feat)
  float*  out_jk =(float*)(arena+75497472);                        //  8,388,608 B (inside dead var_feat)

  // fused CSR build
  hipMemsetAsync(cnt_all,0,(size_t)NT_N*4,stream);
  k_hist3<<<ET_N/256,256,0,stream>>>(dst_vv,dst_iv,dst_vi,cnt_all);
  int nb=NT_N/512;   // 576
  k_scan1<<<nb,512,0,stream>>>(cnt_all,NT_N,rp_all,bsum);
  k_scan2<<<1,1024,0,stream>>>(bsum,boff,nb);
  k_scan3<<<nb,512,0,stream>>>(rp_all,boff,cur_all,NT_N,nb);
  for(int wdx=0;wdx<SC_WIN;wdx++){
    int dlo=wdx*(NT_N/SC_WIN), dhi=(wdx+1)*(NT_N/SC_WIN);
    k_scatter3w<<<ET_N/256,256,0,stream>>>(src_vv,dst_vv,src_iv,dst_iv,src_vi,dst_vi,cur_all,esrc_all,dlo,dhi);
  }

  k_castx<<<(NI_N*64+NV_N*64)/256,256,0,stream>>>(x_instr,x_var,xi,xv);

  // one-time splits for JK weights
  k_split2<<<(192*64+255)/256,256,0,stream>>>(Wqkv,192*64,qkvh,qkvl);
  k_split2<<<(64*64+255)/256,256,0,stream>>>(Wo,64*64,woh,wol);

  FoldArgs fa;
  fa.Wk_i=(const float*)d_in[2]; fa.Wq_i=(const float*)d_in[3]; fa.Wv_i=(const float*)d_in[4];
  fa.bk_i=(const float*)d_in[6]; fa.bq_i=(const float*)d_in[7]; fa.bv_i=(const float*)d_in[8];
  fa.Wk_v=(const float*)d_in[11]; fa.Wq_v=(const float*)d_in[12]; fa.Wv_v=(const float*)d_in[13];
  fa.bk_v=(const float*)d_in[15]; fa.bq_v=(const float*)d_in[16]; fa.bv_v=(const float*)d_in[17];
  fa.arel_vv=(const float*)d_in[20]; fa.mrel_vv=(const float*)d_in[21]; fa.prel_vv=(const float*)d_in[22];
  fa.arel_vi=(const float*)d_in[23]; fa.mrel_vi=(const float*)d_in[24]; fa.prel_vi=(const float*)d_in[25];
  fa.arel_iv=(const float*)d_in[26]; fa.mrel_iv=(const float*)d_in[27]; fa.prel_iv=(const float*)d_in[28];
  fa.Wa_i=(const float*)d_in[5]; fa.Wa_v=(const float*)d_in[14];
  fa.fwh_var=fwh_var; fa.fwl_var=fwl_var; fa.fwh_ins=fwh_ins; fa.fwl_ins=fwl_ins;
  fa.wah_i=wah_i; fa.wal_i=wal_i; fa.wah_v=wah_v; fa.wal_v=wal_v;
  fa.fwb_var=fwb_var; fa.fwb_ins=fwb_ins;
  k_fold6<<<(6*640*64)/256,256,0,stream>>>(fa);

  for(int l=0;l<6;l++){
    k_colres_feat<<<5*CHV+3*CHI,256,0,stream>>>(xv,xi,
        fwh_var+(size_t)l*320*64,fwl_var+(size_t)l*320*64,fwb_var+l*320,
        fwh_ins+(size_t)l*192*64,fwl_ins+(size_t)l*192*64,fwb_ins+l*192,
        var_feat,ins_feat);
    k_edge_all<<<NV_N/4+NI_N/4,256,0,stream>>>(rp_all,esrc_all,var_feat,ins_feat,agg_v,agg_i,NV_N/4);
    k_update2<<<NI_N/64+NV_N/64,256,0,stream>>>(agg_i,agg_v,
        wah_i+(size_t)l*4096,wal_i+(size_t)l*4096,wah_v+(size_t)l*4096,wal_v+(size_t)l*4096,
        ba_i+l*64,ba_v+l*64,skip_i+l,skip_v+l,xi,xv,
        (l>0)?(outs+(size_t)(l-1)*NI_N*64):nullptr,NI_N/64);
  }

  // jumping knowledge + head
  k_colres1<<<3*CHQ,256,0,stream>>>(outs,5*NI_N/64,qkvh,qkvl,bqkv,qkv,192,CHQ);
  k_jk<<<NI_N/4,256,0,stream>>>(qkv,osum,NI_N);
  k_gemm64p<float,float><<<NI_N/64,256,0,stream>>>(osum,NI_N,woh,wol,bo,5.0f,out_jk,64,0,1);
  MlpArgs ma;
  ma.w0=(const float*)d_in[33]; ma.b0=(const float*)d_in[34];
  ma.w1=(const float*)d_in[35]; ma.b1=(const float*)d_in[36];
  ma.w2=(const float*)d_in[37]; ma.b2=(const float*)d_in[38];
  ma.w3=(const float*)d_in[39]; ma.b3=(const float*)d_in[40];
  ma.w4=(const float*)d_in[41]; ma.b4=(const float*)d_in[42];
  ma.w5=(const float*)d_in[43]; ma.b5=(const float*)d_in[44];
  k_mlp<<<NI_N/256,256,0,stream>>>(out_jk,ma,(float*)d_out,NI_N);
}

// Round 7
// 1541.609 us; speedup vs baseline: 1.0442x; 1.0442x over previous
//
#include <hip/hip_runtime.h>
#include <cmath>

typedef _Float16 f16_t;                                         // IEEE fp16
typedef __attribute__((ext_vector_type(8))) short short8;       // MFMA A/B frag (bit container)
typedef __attribute__((ext_vector_type(8))) _Float16 half8;     // MFMA f16 frag
typedef __attribute__((ext_vector_type(4))) float f32x4;        // MFMA C/D frag
typedef _Float16 h2v __attribute__((ext_vector_type(2)));       // packed f16 pair
typedef _Float16 h8 __attribute__((ext_vector_type(8)));        // 16B f16 vector
typedef float f2 __attribute__((ext_vector_type(2)));           // packed f32 pair

#define NI_N 32768
#define NV_N 131072
#define E_VV 1048576
#define E_VI 524288
#define E_IV 524288
#define NT_N (NV_N+NV_N+NI_N)          // 294912 concatenated nodes (vv|iv|vi)
#define ET_N (E_VV+E_IV+E_VI)          // 2097152 concatenated edges
#define SC_WIN 4                        // scatter windows
#define LOG2E 1.4426950408889634f
#define CHV 192                         // row-chunks per var panel (colres)
#define CHI 64                          // row-chunks per ins panel
#define CHQ 256                         // row-chunks per qkv panel
#define EPAD 68                         // LDS transpose row stride (floats)

__device__ __forceinline__ float gelu_f(float x){ return 0.5f*x*(1.0f+erff(x*0.7071067811865476f)); }

// split f32 into hi/lo f16 (hi+lo carries ~22 bits of mantissa)
__device__ __forceinline__ void splitf16(float v, short& hi, short& lo){
  f16_t h=(f16_t)v;
  hi=__builtin_bit_cast(short,h);
  f16_t l=(f16_t)(v-(float)h);
  lo=__builtin_bit_cast(short,l);
}
__device__ __forceinline__ f32x4 mfma16(short8 a, short8 b, f32x4 c){
  return __builtin_amdgcn_mfma_f32_16x16x32_f16(__builtin_bit_cast(half8,a),__builtin_bit_cast(half8,b),c,0,0,0);
}
__device__ __forceinline__ float fexp2(float x){
#if __has_builtin(__builtin_amdgcn_exp2f)
  return __builtin_amdgcn_exp2f(x);
#else
  return exp2f(x);
#endif
}
__device__ __forceinline__ float ldval(const float* p){ return *p; }
__device__ __forceinline__ float ldval(const f16_t* p){ return (float)*p; }
__device__ __forceinline__ void stval(float* p,float v){ *p=v; }
__device__ __forceinline__ void stval(f16_t* p,float v){ *p=(f16_t)v; }

// ---------------- fused CSR build over 3 concatenated edge types ----------------
__global__ __launch_bounds__(256) void k_hist3(const int* __restrict__ dvv,const int* __restrict__ div_,
    const int* __restrict__ dvi,int* __restrict__ cnt){
  int i=blockIdx.x*256+threadIdx.x;
  if(i<E_VV) atomicAdd(&cnt[dvv[i]],1);
  else if(i<E_VV+E_IV) atomicAdd(&cnt[NV_N+div_[i-E_VV]],1);
  else atomicAdd(&cnt[2*NV_N+dvi[i-E_VV-E_IV]],1);
}
__global__ __launch_bounds__(512) void k_scan1(const int* __restrict__ cnt,int N,int* __restrict__ rp,int* __restrict__ bsum){
  __shared__ int sh[512];
  int i=blockIdx.x*512+threadIdx.x;
  int v=(i<N)?cnt[i]:0;
  sh[threadIdx.x]=v; __syncthreads();
  for(int off=1;off<512;off<<=1){
    int t=(threadIdx.x>=(unsigned)off)?sh[threadIdx.x-off]:0; __syncthreads();
    sh[threadIdx.x]+=t; __syncthreads();
  }
  if(i<N) rp[i]=sh[threadIdx.x]-v;
  if(threadIdx.x==511) bsum[blockIdx.x]=sh[511];
}
__global__ __launch_bounds__(1024) void k_scan2(const int* __restrict__ bsum,int* __restrict__ boff,int nb){
  __shared__ int sh[1024];
  int t=threadIdx.x;
  int v=(t<nb)?bsum[t]:0;
  sh[t]=v; __syncthreads();
  for(int off=1;off<1024;off<<=1){
    int x=(t>=(unsigned)off)?sh[t-off]:0; __syncthreads();
    sh[t]+=x; __syncthreads();
  }
  if(t<nb) boff[t]=sh[t]-v;
  if(t==1023) boff[nb]=sh[1023];
}
__global__ __launch_bounds__(512) void k_scan3(int* __restrict__ rp,const int* __restrict__ boff,int* __restrict__ cur,int N,int nb){
  int i=blockIdx.x*512+threadIdx.x;
  if(i<N){ int v=rp[i]+boff[i>>9]; rp[i]=v; cur[i]=v; }
  if(i==0) rp[N]=boff[nb];
}
// scatter stores PRE-SCALED source row offsets (src*stride) so the edge kernel does no mul
__global__ __launch_bounds__(256) void k_scatter3w(const int* __restrict__ svv,const int* __restrict__ dvv,
    const int* __restrict__ siv,const int* __restrict__ div_,
    const int* __restrict__ svi,const int* __restrict__ dvi,
    int* __restrict__ cur,int* __restrict__ esrc,int dlo,int dhi){
  int i=blockIdx.x*256+threadIdx.x;
  int d,s;
  if(i<E_VV){ d=dvv[i]; if(d<dlo||d>=dhi) return; s=svv[i]*320; }
  else if(i<E_VV+E_IV){ int j=i-E_VV; d=NV_N+div_[j]; if(d<dlo||d>=dhi) return; s=siv[j]*192; }
  else { int j=i-E_VV-E_IV; d=2*NV_N+dvi[j]; if(d<dlo||d>=dhi) return; s=svi[j]*320; }
  int p=atomicAdd(&cur[d],1); esrc[p]=s;
}

// initial cast: f32 inputs -> f16 x buffers
__global__ __launch_bounds__(256) void k_castx(const float* __restrict__ xi_in,const float* __restrict__ xv_in,
    f16_t* __restrict__ xi,f16_t* __restrict__ xv){
  int i=blockIdx.x*256+threadIdx.x;
  if(i<NI_N*64) xi[i]=(f16_t)xi_in[i];
  else { int j=i-NI_N*64; xv[j]=(f16_t)xv_in[j]; }
}

// ---------------- weight folding for ALL 6 layers in one launch ----------------
// Contiguous block layout: q(64) | k(64) | v(64) [| k2 | v2] so the edge kernel
// loads per-head 16B k-rows and v-rows. q columns scaled by LOG2E for exp2 softmax.
struct FoldArgs{
  const float *Wk_i,*Wq_i,*Wv_i,*bk_i,*bq_i,*bv_i;
  const float *Wk_v,*Wq_v,*Wv_v,*bk_v,*bq_v,*bv_v;
  const float *arel_vv,*mrel_vv,*prel_vv,*arel_vi,*mrel_vi,*prel_vi,*arel_iv,*mrel_iv,*prel_iv;
  const float *Wa_i,*Wa_v;
  short *fwh_var,*fwl_var,*fwh_ins,*fwl_ins,*wah_i,*wal_i,*wah_v,*wal_v;
  float *fwb_var,*fwb_ins;
};
__global__ __launch_bounds__(256) void k_fold6(FoldArgs fa){
  int gid=blockIdx.x*256+threadIdx.x;
  if(gid>=6*640*64) return;
  int l=gid/(640*64);
  int rem=gid-l*640*64;
  int r=rem>>6, c=rem&63;
  if(r>=512){
    int ro=r&63;
    const float* W=(r<576)?fa.Wa_i:fa.Wa_v;
    short *sh=((r<576)?fa.wah_i:fa.wah_v)+l*4096, *sl=((r<576)?fa.wal_i:fa.wal_v)+l*4096;
    short h,lo; splitf16(W[l*4096+ro*64+c],h,lo);
    sh[ro*64+c]=h; sl[ro*64+c]=lo;
    return;
  }
  const float *W,*B,*rel=nullptr,*prl=nullptr;
  short *sh,*sl; float *fwb; int orow; bool isq=false;
  if(r<320){
    sh=fa.fwh_var+l*320*64; sl=fa.fwl_var+l*320*64; fwb=fa.fwb_var+l*320; orow=r;
    if(r<64){ W=fa.Wq_v; B=fa.bq_v; isq=true; }
    else if(r<128){ W=fa.Wk_v; B=fa.bk_v; rel=fa.arel_vv; prl=fa.prel_vv; }
    else if(r<192){ W=fa.Wv_v; B=fa.bv_v; rel=fa.mrel_vv; }
    else if(r<256){ W=fa.Wk_v; B=fa.bk_v; rel=fa.arel_vi; prl=fa.prel_vi; }
    else         { W=fa.Wv_v; B=fa.bv_v; rel=fa.mrel_vi; }
  }else{
    int rr=r-320; sh=fa.fwh_ins+l*192*64; sl=fa.fwl_ins+l*192*64; fwb=fa.fwb_ins+l*192; orow=rr;
    if(rr<64){ W=fa.Wq_i; B=fa.bq_i; isq=true; }
    else if(rr<128){ W=fa.Wk_i; B=fa.bk_i; rel=fa.arel_iv; prl=fa.prel_iv; }
    else           { W=fa.Wv_i; B=fa.bv_i; rel=fa.mrel_iv; }
  }
  int d=orow&63;
  float val,bval;
  if(!rel){
    val=W[l*4096+d*64+c]; bval=B[l*64+d];
  }else{
    int h=d>>3, e=d&7;
    float s=prl?prl[l*8+h]*0.3535533905932738f:1.0f;
    float acc=0.f,bacc=0.f;
    #pragma unroll
    for(int dd=0;dd<8;dd++){
      float rv=rel[l*512+h*64+dd*8+e];
      acc += W[l*4096+(h*8+dd)*64+c]*rv;
      bacc+= B[l*64+h*8+dd]*rv;
    }
    val=acc*s; bval=bacc*s;
  }
  if(isq){ val*=LOG2E; bval*=LOG2E; }
  short h2q,lo2; splitf16(val,h2q,lo2);
  sh[orow*64+c]=h2q; sl[orow*64+c]=lo2;
  if(c==0) fwb[orow]=bval;
}

__global__ __launch_bounds__(256) void k_split2(const float* __restrict__ W,int n,short* __restrict__ hi,short* __restrict__ lo){
  int i=blockIdx.x*256+threadIdx.x;
  if(i<n){ short h,l2; splitf16(W[i],h,l2); hi[i]=h; lo[i]=l2; }
}

// ---------------- column-resident GEMM: B frags live in registers, block grid-strides rows ----------------
__device__ __forceinline__ void colres_body(const f16_t* __restrict__ A,int nrb,
    const short* __restrict__ Bh,const short* __restrict__ Bl,
    const float* __restrict__ bias,f16_t* __restrict__ out,int octot,int ocol0,
    int c,int CH,int wave,int lane,int m,int quad,f16_t (*rep)[72])
{
  short8 bhi[4][2], blo[4][2]; float bb[4];
  #pragma unroll
  for(int ot=0;ot<4;ot++){
    size_t o=(size_t)(ocol0+ot*16+m)*64+quad*8;
    bhi[ot][0]=*(const short8*)(Bh+o);    bhi[ot][1]=*(const short8*)(Bh+o+32);
    blo[ot][0]=*(const short8*)(Bl+o);    blo[ot][1]=*(const short8*)(Bl+o+32);
    bb[ot]=bias[ocol0+ot*16+m];
  }
  int rr0=lane>>3, seg=lane&7;
  for(int rb=c;rb<nrb;rb+=CH){
    int row0=rb*64+wave*16;
    const f16_t* ap=A+(size_t)(row0+m)*64+quad*8;
    short8 a0=*(const short8*)(const void*)ap;
    short8 a1=*(const short8*)(const void*)(ap+32);
    f32x4 acc[4];
    #pragma unroll
    for(int ot=0;ot<4;ot++){ f32x4 t={bb[ot],bb[ot],bb[ot],bb[ot]}; acc[ot]=t; }
    #pragma unroll
    for(int ot=0;ot<4;ot++){
      acc[ot]=mfma16(a0,blo[ot][0],acc[ot]);
      acc[ot]=mfma16(a0,bhi[ot][0],acc[ot]);
      acc[ot]=mfma16(a1,blo[ot][1],acc[ot]);
      acc[ot]=mfma16(a1,bhi[ot][1],acc[ot]);
    }
    #pragma unroll
    for(int ot=0;ot<4;ot++)
      #pragma unroll
      for(int r=0;r<4;r++)
        rep[quad*4+r][ot*16+m]=(f16_t)acc[ot][r];
    #pragma unroll
    for(int it=0;it<2;it++){
      int rr=it*8+rr0;
      h8 vals=*(const h8*)&rep[rr][seg*8];
      *(h8*)(out+(size_t)(row0+rr)*octot+ocol0+seg*8)=vals;
    }
  }
}

// fused feature GEMM: blocks [0,5*CHV) var panels, rest ins panels
__global__ __launch_bounds__(256) void k_colres_feat(const f16_t* __restrict__ Av,const f16_t* __restrict__ Ai,
    const short* __restrict__ Bvh,const short* __restrict__ Bvl,const float* __restrict__ biasv,
    const short* __restrict__ Bih,const short* __restrict__ Bil,const float* __restrict__ biasi,
    f16_t* __restrict__ outv,f16_t* __restrict__ outi)
{
  __shared__ f16_t rep[4][16][72];
  const int wave=threadIdx.x>>6, lane=threadIdx.x&63;
  const int m=lane&15, quad=lane>>4;
  int bx=blockIdx.x;
  if(bx<5*CHV){
    int pan=bx/CHV, c=bx%CHV;
    colres_body(Av,NV_N/64,Bvh,Bvl,biasv,outv,320,pan*64,c,CHV,wave,lane,m,quad,rep[wave]);
  }else{
    bx-=5*CHV;
    int pan=bx/CHI, c=bx%CHI;
    colres_body(Ai,NI_N/64,Bih,Bil,biasi,outi,192,pan*64,c,CHI,wave,lane,m,quad,rep[wave]);
  }
}

// generic single-input column-resident GEMM (used for JK qkv)
__global__ __launch_bounds__(256) void k_colres1(const f16_t* __restrict__ A,int nrb,
    const short* __restrict__ Bh,const short* __restrict__ Bl,
    const float* __restrict__ bias,f16_t* __restrict__ out,int octot,int CH)
{
  __shared__ f16_t rep[4][16][72];
  const int wave=threadIdx.x>>6, lane=threadIdx.x&63;
  const int m=lane&15, quad=lane>>4;
  int pan=blockIdx.x/CH, c=blockIdx.x%CH;
  colres_body(A,nrb,Bh,Bl,bias,out,octot,pan*64,c,CH,wave,lane,m,quad,rep[wave]);
}

// ---------------- legacy GEMM body (float A path for osum @ Wo) ----------------
template<typename AT, typename OT>
__device__ __forceinline__ void gemm_body(const AT* __restrict__ A,int row0,
    const short* __restrict__ Bh,const short* __restrict__ Bl,
    const float* __restrict__ bias,float bias_scale,
    OT* __restrict__ out,int octot,int ocol0,int npanels,int m,int quad,int lane,
    f16_t (*rep)[72])
{
  const AT* ap=A+(size_t)(row0+m)*64+quad*8;
  constexpr bool AF16 = (sizeof(AT)==2);
  short8 ahi[2], alo[2];
  if constexpr(AF16){
    #pragma unroll
    for(int kf=0;kf<2;kf++) ahi[kf]=*(const short8*)(const void*)(ap+kf*32);
  }else{
    #pragma unroll
    for(int kf=0;kf<2;kf++){
      short8 th,tl;
      #pragma unroll
      for(int j=0;j<8;j++){ short h,l2; splitf16(ldval(&ap[kf*32+j]),h,l2); th[j]=h; tl[j]=l2; }
      ahi[kf]=th; alo[kf]=tl;
    }
  }
  for(int pan=0;pan<npanels;pan++){
    int colbase=pan*64;
    short8 bhi[4][2], blo[4][2];
    #pragma unroll
    for(int ot=0;ot<4;ot++){
      size_t o=(size_t)(colbase+ot*16+m)*64+quad*8;
      #pragma unroll
      for(int kf=0;kf<2;kf++){
        bhi[ot][kf]=*(const short8*)(Bh+o+kf*32);
        blo[ot][kf]=*(const short8*)(Bl+o+kf*32);
      }
    }
    f32x4 acc[4];
    #pragma unroll
    for(int ot=0;ot<4;ot++){
      float bv=bias[colbase+ot*16+m]*bias_scale;
      acc[ot][0]=bv; acc[ot][1]=bv; acc[ot][2]=bv; acc[ot][3]=bv;
    }
    #pragma unroll
    for(int ot=0;ot<4;ot++){
      #pragma unroll
      for(int kf=0;kf<2;kf++){
        if constexpr(!AF16) acc[ot]=mfma16(alo[kf],bhi[ot][kf],acc[ot]);
        acc[ot]=mfma16(ahi[kf],blo[ot][kf],acc[ot]);
        acc[ot]=mfma16(ahi[kf],bhi[ot][kf],acc[ot]);
      }
    }
    if constexpr(sizeof(OT)==2){
      #pragma unroll
      for(int ot=0;ot<4;ot++)
        #pragma unroll
        for(int r=0;r<4;r++)
          rep[quad*4+r][ot*16+m]=(f16_t)acc[ot][r];
      #pragma unroll
      for(int it=0;it<2;it++){
        int rr=it*8+(lane>>3), seg=lane&7;
        h8 vals=*(const h8*)&rep[rr][seg*8];
        *(h8*)(out+(size_t)(row0+rr)*octot+ocol0+colbase+seg*8)=vals;
      }
    }else{
      #pragma unroll
      for(int ot=0;ot<4;ot++){
        int col=ocol0+colbase+ot*16+m;
        #pragma unroll
        for(int r=0;r<4;r++){
          int row=row0+quad*4+r;
          stval(&out[(size_t)row*octot+col],acc[ot][r]);
        }
      }
    }
  }
}

template<typename AT, typename OT>
__global__ __launch_bounds__(256) void k_gemm64p(const AT* __restrict__ A,int N,
    const short* __restrict__ Bh,const short* __restrict__ Bl,
    const float* __restrict__ bias,float bias_scale,
    OT* __restrict__ out,int octot,int ocol0,int npanels)
{
  __shared__ f16_t rep[4][16][72];
  const int wave=threadIdx.x>>6, lane=threadIdx.x&63;
  const int m=lane&15, quad=lane>>4;
  const int row0=blockIdx.x*64+wave*16;
  if(row0>=N) return;
  gemm_body<AT,OT>(A,row0,Bh,Bl,bias,bias_scale,out,octot,ocol0,npanels,m,quad,lane,rep[wave]);
}

// ---------------- fused per-layer update (instr blocks then var blocks), x/agg f16, LDS-repacked I/O ----------------
__global__ __launch_bounds__(256) void k_update2(const f16_t* __restrict__ agg_i,const f16_t* __restrict__ agg_v,
    const short* __restrict__ wah_i,const short* __restrict__ wal_i,
    const short* __restrict__ wah_v,const short* __restrict__ wal_v,
    const float* __restrict__ ba_i,const float* __restrict__ ba_v,
    const float* __restrict__ skip_i,const float* __restrict__ skip_v,
    f16_t* __restrict__ x_i,f16_t* __restrict__ x_v,
    f16_t* __restrict__ outs,int nbi)
{
  __shared__ f16_t rep[4][16][72];
  const int wave=threadIdx.x>>6, lane=threadIdx.x&63;
  const int m=lane&15, quad=lane>>4;
  const bool isI=(int)blockIdx.x<nbi;
  const int row0=(isI?blockIdx.x:(blockIdx.x-nbi))*64+wave*16;
  const f16_t* agg=isI?agg_i:agg_v;
  const short* Wah=isI?wah_i:wah_v;
  const short* Wal=isI?wal_i:wal_v;
  const float* ba=isI?ba_i:ba_v;
  const float* skip=isI?skip_i:skip_v;
  f16_t* x=isI?x_i:x_v;
  f16_t* oo=isI?outs:nullptr;
  f16_t (*R)[72]=rep[wave];
  short8 bhi[4][2], blo[4][2];
  #pragma unroll
  for(int ot=0;ot<4;ot++){
    size_t o=(size_t)(ot*16+m)*64+quad*8;
    #pragma unroll
    for(int kf=0;kf<2;kf++){
      bhi[ot][kf]=*(const short8*)(Wah+o+kf*32);
      blo[ot][kf]=*(const short8*)(Wal+o+kf*32);
    }
  }
  const f16_t* ap=agg+(size_t)(row0+m)*64+quad*8;
  short8 ahi[2], alo[2];
  #pragma unroll
  for(int kf=0;kf<2;kf++){
    short8 th,tl;
    #pragma unroll
    for(int j=0;j<8;j++){ short h,l2; splitf16(gelu_f((float)ap[kf*32+j]),h,l2); th[j]=h; tl[j]=l2; }
    ahi[kf]=th; alo[kf]=tl;
  }
  // stage x rows into LDS (wide loads)
  int rr0=lane>>3, seg=lane&7;
  h8 x0=*(const h8*)(x+(size_t)(row0+rr0)*64+seg*8);
  h8 x1=*(const h8*)(x+(size_t)(row0+8+rr0)*64+seg*8);
  *(h8*)&R[rr0][seg*8]=x0;
  *(h8*)&R[8+rr0][seg*8]=x1;
  f32x4 acc[4];
  #pragma unroll
  for(int ot=0;ot<4;ot++){
    float bv=ba[ot*16+m];
    acc[ot][0]=bv; acc[ot][1]=bv; acc[ot][2]=bv; acc[ot][3]=bv;
  }
  #pragma unroll
  for(int ot=0;ot<4;ot++){
    #pragma unroll
    for(int kf=0;kf<2;kf++){
      acc[ot]=mfma16(alo[kf],bhi[ot][kf],acc[ot]);
      acc[ot]=mfma16(ahi[kf],blo[ot][kf],acc[ot]);
      acc[ot]=mfma16(ahi[kf],bhi[ot][kf],acc[ot]);
    }
  }
  float s=1.0f/(1.0f+__expf(-skip[0]));
  #pragma unroll
  for(int ot=0;ot<4;ot++){
    int col=ot*16+m;
    #pragma unroll
    for(int r=0;r<4;r++){
      int row=quad*4+r;
      float xn=s*acc[ot][r]+(1.0f-s)*(float)R[row][col];
      R[row][col]=(f16_t)xn;
    }
  }
  h8 o0=*(const h8*)&R[rr0][seg*8];
  h8 o1=*(const h8*)&R[8+rr0][seg*8];
  *(h8*)(x+(size_t)(row0+rr0)*64+seg*8)=o0;
  *(h8*)(x+(size_t)(row0+8+rr0)*64+seg*8)=o1;
  if(oo){
    *(h8*)(oo+(size_t)(row0+rr0)*64+seg*8)=o0;
    *(h8*)(oo+(size_t)(row0+8+rr0)*64+seg*8)=o1;
  }
}

// ---------------- edge attention: lane = (e_slot, head); defer-max online softmax ----------------
// esrc holds PRE-SCALED row offsets. Layout q|k|v blocks. q pre-scaled by LOG2E -> exp2.
// Defer-max (T13): keep m fixed, w=exp2(p-m) bounded by 2^8; rescale only when p-m>8
// (rare branch, wave-skipped via execz). Mathematically exact.
__device__ __forceinline__ float dot8(h8 k,h2v q0,h2v q1,h2v q2,h2v q3){
#if __has_builtin(__builtin_amdgcn_fdot2)
  float p=__builtin_amdgcn_fdot2((h2v){k[0],k[1]},q0,0.f,false);
  p=__builtin_amdgcn_fdot2((h2v){k[2],k[3]},q1,p,false);
  p=__builtin_amdgcn_fdot2((h2v){k[4],k[5]},q2,p,false);
  p=__builtin_amdgcn_fdot2((h2v){k[6],k[7]},q3,p,false);
  return p;
#else
  return (float)k[0]*(float)q0[0]+(float)k[1]*(float)q0[1]
        +(float)k[2]*(float)q1[0]+(float)k[3]*(float)q1[1]
        +(float)k[4]*(float)q2[0]+(float)k[5]*(float)q2[1]
        +(float)k[6]*(float)q3[0]+(float)k[7]*(float)q3[1];
#endif
}

__device__ __forceinline__ float edge_agg_eh(const int* __restrict__ rp,const int* __restrict__ es,
    const f16_t* __restrict__ sf,int koff,int voff,int n,int e_slot,int h,int lane,
    h2v q0,h2v q1,h2v q2,h2v q3,float* __restrict__ L)
{
  int b=__builtin_amdgcn_readfirstlane(rp[n]);
  int e=__builtin_amdgcn_readfirstlane(rp[n+1]);
  if(b==e) return 0.f;
  float m=-1e30f, ls=0.f;
  f2 A0={0.f,0.f},A1={0.f,0.f},A2={0.f,0.f},A3={0.f,0.f};
  const int hb=h*8;
  for(int i=b;i<e;i+=8){
    int eidx=i+e_slot;
    bool valid=eidx<e;
    int ec=valid?eidx:(e-1);
    int off=es[ec];
    const f16_t* kp=sf+(size_t)(unsigned)off+koff+hb;
    h8 kv=*(const h8*)kp;
    h8 vv=*(const h8*)(sf+(size_t)(unsigned)off+voff+hb);
    float p=dot8(kv,q0,q1,q2,q3);
    float d=p-m;
    if(__builtin_expect(d>8.f,0)){
      // rare rescale: first iteration (m=-1e30 -> sc=0, clean init) or max jump
      float sc=fexp2(-d);
      ls*=sc;
      f2 S={sc,sc};
      A0*=S; A1*=S; A2*=S; A3*=S;
      m=p; d=0.f;
    }
    float w=valid?fexp2(d):0.f;      // d<=8 -> w<=256, f32-safe
    ls+=w;
    f2 W={w,w};
    A0+=W*(f2){(float)vv[0],(float)vv[1]};
    A1+=W*(f2){(float)vv[2],(float)vv[3]};
    A2+=W*(f2){(float)vv[4],(float)vv[5]};
    A3+=W*(f2){(float)vv[6],(float)vv[7]};
  }
  // combine across e_slot (lanes xor 8/16/32 share the same head h)
  float mall=fmaxf(m,__shfl_xor(m,8));
  mall=fmaxf(mall,__shfl_xor(mall,16));
  mall=fmaxf(mall,__shfl_xor(mall,32));
  float scl=fexp2(m-mall);
  ls*=scl;
  float lsall=ls+__shfl_xor(ls,8);
  lsall+=__shfl_xor(lsall,16);
  lsall+=__shfl_xor(lsall,32);
  f2 S2={scl,scl};
  A0*=S2; A1*=S2; A2*=S2; A3*=S2;
  // LDS transpose: write [e_slot][h*8+d] at EPAD stride, read [e][lane]
  float* wp=L+e_slot*EPAD+hb;
  *(f32x4*)wp=(f32x4){A0[0],A0[1],A1[0],A1[1]};
  *(f32x4*)(wp+4)=(f32x4){A2[0],A2[1],A3[0],A3[1]};
  __asm__ volatile("s_waitcnt lgkmcnt(0)" ::: "memory");
  float r=0.f;
  #pragma unroll
  for(int ee=0;ee<8;ee++) r+=L[ee*EPAD+lane];
  float lsr=__shfl(lsall,lane>>3);   // ls for head (lane>>3) lives at lane (lane>>3)
  return r/(lsr+1e-16f);             // degree 0 -> early return; matches PyG semantics
}

// fused edge kernel: blocks [0,nbv) var destinations (vv+iv), rest instr destinations (vi)
__global__ __launch_bounds__(256) void k_edge_all(const int* __restrict__ rp_all,const int* __restrict__ es,
    const f16_t* __restrict__ var_feat,const f16_t* __restrict__ ins_feat,
    f16_t* __restrict__ agg_v,f16_t* __restrict__ agg_i,int nbv)
{
  __shared__ float lds[4][8*EPAD];
  int wave=threadIdx.x>>6, lane=threadIdx.x&63;
  int e_slot=lane>>3, h=lane&7;
  float* L=lds[wave];
  if((int)blockIdx.x<nbv){
    int n=blockIdx.x*4+wave;
    const f16_t* qp=var_feat+(size_t)n*320+h*8;
    h8 qv=*(const h8*)qp;
    h2v q0={qv[0],qv[1]},q1={qv[2],qv[3]},q2={qv[4],qv[5]},q3={qv[6],qv[7]};
    float r1=edge_agg_eh(rp_all,es,var_feat,64,128,n,e_slot,h,lane,q0,q1,q2,q3,L);
    float r2=edge_agg_eh(rp_all+NV_N,es,ins_feat,64,128,n,e_slot,h,lane,q0,q1,q2,q3,L);
    agg_v[(size_t)n*64+lane]=(f16_t)(r1+r2);
  }else{
    int n=(blockIdx.x-nbv)*4+wave;
    const f16_t* qp=ins_feat+(size_t)n*192+h*8;
    h8 qv=*(const h8*)qp;
    h2v q0={qv[0],qv[1]},q1={qv[2],qv[3]},q2={qv[4],qv[5]},q3={qv[6],qv[7]};
    float r=edge_agg_eh(rp_all+2*NV_N,es,var_feat,192,256,n,e_slot,h,lane,q0,q1,q2,q3,L);
    agg_i[(size_t)n*64+lane]=(f16_t)r;
  }
}

// ---------------- jumping-knowledge 5x5 attention, one wave per node
__global__ __launch_bounds__(256) void k_jk(const f16_t* __restrict__ qkv,float* __restrict__ osum,int n_nodes){
  int wave=threadIdx.x>>6, lane=threadIdx.x&63;
  int n=blockIdx.x*4+wave;
  if(n>=n_nodes) return;
  float q[5],k[5],v[5];
  #pragma unroll
  for(int s=0;s<5;s++){
    const f16_t* p=qkv+((size_t)s*n_nodes+n)*192;
    q[s]=(float)p[lane]; k[s]=(float)p[64+lane]; v[s]=(float)p[128+lane];
  }
  float sc[5][5];
  #pragma unroll
  for(int s=0;s<5;s++)
    #pragma unroll
    for(int t=0;t<5;t++){
      float x=q[s]*k[t];
      x+=__shfl_xor(x,1); x+=__shfl_xor(x,2); x+=__shfl_xor(x,4);
      sc[s][t]=x*0.3535533905932738f;
    }
  float os=0.f;
  #pragma unroll
  for(int s=0;s<5;s++){
    float m=sc[s][0];
    #pragma unroll
    for(int t=1;t<5;t++) m=fmaxf(m,sc[s][t]);
    float den=0.f, acc=0.f;
    #pragma unroll
    for(int t=0;t<5;t++){ float e=__expf(sc[s][t]-m); den+=e; acc+=e*v[t]; }
    os+=acc/den;
  }
  osum[(size_t)n*64+lane]=os;
}

// ---------------- MLP head ----------------
struct MlpArgs{ const float *w0,*b0,*w1,*b1,*w2,*b2,*w3,*b3,*w4,*b4,*w5,*b5; };
__global__ __launch_bounds__(256) void k_mlp(const float* __restrict__ in,MlpArgs ma,float* __restrict__ out,int N){
  __shared__ float sw0[2048],sb0[32],sw1[512],sb1[16],sw2[128],sb2[8],sw3[32],sb3[4],sw4[8],sb4[2],sw5[2],sb5[1];
  for(int i=threadIdx.x;i<2048;i+=256) sw0[i]=ma.w0[i];
  for(int i=threadIdx.x;i<512;i+=256)  sw1[i]=ma.w1[i];
  if(threadIdx.x<128) sw2[threadIdx.x]=ma.w2[threadIdx.x];
  if(threadIdx.x<32){ sb0[threadIdx.x]=ma.b0[threadIdx.x]; sw3[threadIdx.x]=ma.w3[threadIdx.x]; }
  if(threadIdx.x<16) sb1[threadIdx.x]=ma.b1[threadIdx.x];
  if(threadIdx.x<8){ sb2[threadIdx.x]=ma.b2[threadIdx.x]; sw4[threadIdx.x]=ma.w4[threadIdx.x]; }
  if(threadIdx.x<4) sb3[threadIdx.x]=ma.b3[threadIdx.x];
  if(threadIdx.x<2){ sb4[threadIdx.x]=ma.b4[threadIdx.x]; sw5[threadIdx.x]=ma.w5[threadIdx.x]; }
  if(threadIdx.x==0) sb5[0]=ma.b5[0];
  __syncthreads();
  int n=blockIdx.x*256+threadIdx.x;
  if(n>=N) return;
  float a[64];
  const f32x4* p4=(const f32x4*)(in+(size_t)n*64);
  #pragma unroll
  for(int j=0;j<16;j++){ f32x4 t=p4[j]; a[4*j]=t[0]; a[4*j+1]=t[1]; a[4*j+2]=t[2]; a[4*j+3]=t[3]; }
  float h1[32];
  #pragma unroll
  for(int o=0;o<32;o++){ float s=sb0[o];
    #pragma unroll
    for(int c=0;c<64;c++) s+=a[c]*sw0[o*64+c];
    h1[o]=gelu_f(s); }
  float h2q[16];
  #pragma unroll
  for(int o=0;o<16;o++){ float s=sb1[o];
    #pragma unroll
    for(int c=0;c<32;c++) s+=h1[c]*sw1[o*32+c];
    h2q[o]=gelu_f(s); }
  float h3[8];
  #pragma unroll
  for(int o=0;o<8;o++){ float s=sb2[o];
    #pragma unroll
    for(int c=0;c<16;c++) s+=h2q[c]*sw2[o*16+c];
    h3[o]=gelu_f(s); }
  float h4[4];
  #pragma unroll
  for(int o=0;o<4;o++){ float s=sb3[o];
    #pragma unroll
    for(int c=0;c<8;c++) s+=h3[c]*sw3[o*8+c];
    h4[o]=gelu_f(s); }
  float h5[2];
  #pragma unroll
  for(int o=0;o<2;o++){ float s=sb4[o];
    #pragma unroll
    for(int c=0;c<4;c++) s+=h4[c]*sw4[o*4+c];
    h5[o]=gelu_f(s); }
  float r=sb5[0]+h5[0]*sw5[0]+h5[1]*sw5[1];
  out[n]=r;
}

// ================= host launcher =================
extern "C" void kernel_launch(void* const* d_in,const int* in_sizes,int n_in,
                              void* d_out,int out_size,void* d_ws,size_t ws_size,
                              hipStream_t stream){
  (void)in_sizes;(void)n_in;(void)out_size;(void)ws_size;
  const float* x_instr=(const float*)d_in[0];
  const float* x_var  =(const float*)d_in[1];
  const float* ba_i=(const float*)d_in[9];
  const float* skip_i=(const float*)d_in[10];
  const float* ba_v=(const float*)d_in[18];
  const float* skip_v=(const float*)d_in[19];
  const float* Wqkv=(const float*)d_in[29];
  const float* bqkv=(const float*)d_in[30];
  const float* Wo=(const float*)d_in[31];
  const float* bo=(const float*)d_in[32];
  const int* src_vv=(const int*)d_in[45];
  const int* dst_vv=(const int*)d_in[46];
  const int* src_vi=(const int*)d_in[47];
  const int* dst_vi=(const int*)d_in[48];
  const int* src_iv=(const int*)d_in[49];
  const int* dst_iv=(const int*)d_in[50];

  char* w=(char*)d_ws;
  auto alloc=[&](size_t b)->char*{ char* p=w; w+=(b+255)&~(size_t)255; return p; };
  // ---- fused CSR arrays (~12 MB) ----
  int* rp_all=(int*)alloc((size_t)(NT_N+1)*4);
  int* cnt_all=(int*)alloc((size_t)NT_N*4);
  int* cur_all=(int*)alloc((size_t)NT_N*4);
  int* bsum =(int*)alloc(640*4);
  int* boff =(int*)alloc(640*4);
  int* esrc_all=(int*)alloc((size_t)ET_N*4);
  // ---- folded + pre-split weights for all 6 layers (~2.5 MB) ----
  short* fwh_var=(short*)alloc((size_t)6*320*64*2);
  short* fwl_var=(short*)alloc((size_t)6*320*64*2);
  float* fwb_var=(float*)alloc((size_t)6*320*4);
  short* fwh_ins=(short*)alloc((size_t)6*192*64*2);
  short* fwl_ins=(short*)alloc((size_t)6*192*64*2);
  float* fwb_ins=(float*)alloc((size_t)6*192*4);
  short* wah_i=(short*)alloc((size_t)6*64*64*2);
  short* wal_i=(short*)alloc((size_t)6*64*64*2);
  short* wah_v=(short*)alloc((size_t)6*64*64*2);
  short* wal_v=(short*)alloc((size_t)6*64*64*2);
  short* qkvh=(short*)alloc(192*64*2);
  short* qkvl=(short*)alloc(192*64*2);
  short* woh=(short*)alloc(64*64*2);
  short* wol=(short*)alloc(64*64*2);
  // ---- persistent across phases: outs (f16, 21 MB) ----
  f16_t* outs=(f16_t*)alloc((size_t)5*NI_N*64*2);
  // ---- arena (140 MB), phase-overlaid ----
  char* arena=alloc((size_t)146800640);
  f16_t*  xv      =(f16_t*)(arena);                                // 16,777,216 B
  f16_t*  xi      =(f16_t*)(arena+16777216);                       //  4,194,304 B
  f16_t*  var_feat=(f16_t*)(arena+20971520);                       // 83,886,080 B (stride 320: q | k_vv | v_vv | k_vi | v_vi)
  f16_t*  ins_feat=(f16_t*)(arena+104857600);                      // 12,582,912 B (stride 192: q | k | v)
  f16_t*  agg_v   =(f16_t*)(arena+117440512);                      // 16,777,216 B
  f16_t*  agg_i   =(f16_t*)(arena+134217728);                      //  4,194,304 B
  // JK phase overlays (xv/xi/var_feat dead by then):
  f16_t*  qkv    =(f16_t*)(arena);                                 // 62,914,560 B
  float*  osum   =(float*)(arena+67108864);                        //  8,388,608 B (inside dead var_feat)
  float*  out_jk =(float*)(arena+75497472);                        //  8,388,608 B (inside dead var_feat)

  // fused CSR build
  hipMemsetAsync(cnt_all,0,(size_t)NT_N*4,stream);
  k_hist3<<<ET_N/256,256,0,stream>>>(dst_vv,dst_iv,dst_vi,cnt_all);
  int nb=NT_N/512;   // 576
  k_scan1<<<nb,512,0,stream>>>(cnt_all,NT_N,rp_all,bsum);
  k_scan2<<<1,1024,0,stream>>>(bsum,boff,nb);
  k_scan3<<<nb,512,0,stream>>>(rp_all,boff,cur_all,NT_N,nb);
  for(int wdx=0;wdx<SC_WIN;wdx++){
    int dlo=wdx*(NT_N/SC_WIN), dhi=(wdx+1)*(NT_N/SC_WIN);
    k_scatter3w<<<ET_N/256,256,0,stream>>>(src_vv,dst_vv,src_iv,dst_iv,src_vi,dst_vi,cur_all,esrc_all,dlo,dhi);
  }

  k_castx<<<(NI_N*64+NV_N*64)/256,256,0,stream>>>(x_instr,x_var,xi,xv);

  // one-time splits for JK weights
  k_split2<<<(192*64+255)/256,256,0,stream>>>(Wqkv,192*64,qkvh,qkvl);
  k_split2<<<(64*64+255)/256,256,0,stream>>>(Wo,64*64,woh,wol);

  FoldArgs fa;
  fa.Wk_i=(const float*)d_in[2]; fa.Wq_i=(const float*)d_in[3]; fa.Wv_i=(const float*)d_in[4];
  fa.bk_i=(const float*)d_in[6]; fa.bq_i=(const float*)d_in[7]; fa.bv_i=(const float*)d_in[8];
  fa.Wk_v=(const float*)d_in[11]; fa.Wq_v=(const float*)d_in[12]; fa.Wv_v=(const float*)d_in[13];
  fa.bk_v=(const float*)d_in[15]; fa.bq_v=(const float*)d_in[16]; fa.bv_v=(const float*)d_in[17];
  fa.arel_vv=(const float*)d_in[20]; fa.mrel_vv=(const float*)d_in[21]; fa.prel_vv=(const float*)d_in[22];
  fa.arel_vi=(const float*)d_in[23]; fa.mrel_vi=(const float*)d_in[24]; fa.prel_vi=(const float*)d_in[25];
  fa.arel_iv=(const float*)d_in[26]; fa.mrel_iv=(const float*)d_in[27]; fa.prel_iv=(const float*)d_in[28];
  fa.Wa_i=(const float*)d_in[5]; fa.Wa_v=(const float*)d_in[14];
  fa.fwh_var=fwh_var; fa.fwl_var=fwl_var; fa.fwh_ins=fwh_ins; fa.fwl_ins=fwl_ins;
  fa.wah_i=wah_i; fa.wal_i=wal_i; fa.wah_v=wah_v; fa.wal_v=wal_v;
  fa.fwb_var=fwb_var; fa.fwb_ins=fwb_ins;
  k_fold6<<<(6*640*64)/256,256,0,stream>>>(fa);

  for(int l=0;l<6;l++){
    k_colres_feat<<<5*CHV+3*CHI,256,0,stream>>>(xv,xi,
        fwh_var+(size_t)l*320*64,fwl_var+(size_t)l*320*64,fwb_var+l*320,
        fwh_ins+(size_t)l*192*64,fwl_ins+(size_t)l*192*64,fwb_ins+l*192,
        var_feat,ins_feat);
    k_edge_all<<<NV_N/4+NI_N/4,256,0,stream>>>(rp_all,esrc_all,var_feat,ins_feat,agg_v,agg_i,NV_N/4);
    k_update2<<<NI_N/64+NV_N/64,256,0,stream>>>(agg_i,agg_v,
        wah_i+(size_t)l*4096,wal_i+(size_t)l*4096,wah_v+(size_t)l*4096,wal_v+(size_t)l*4096,
        ba_i+l*64,ba_v+l*64,skip_i+l,skip_v+l,xi,xv,
        (l>0)?(outs+(size_t)(l-1)*NI_N*64):nullptr,NI_N/64);
  }

  // jumping knowledge + head
  k_colres1<<<3*CHQ,256,0,stream>>>(outs,5*NI_N/64,qkvh,qkvl,bqkv,qkv,192,CHQ);
  k_jk<<<NI_N/4,256,0,stream>>>(qkv,osum,NI_N);
  k_gemm64p<float,float><<<NI_N/64,256,0,stream>>>(osum,NI_N,woh,wol,bo,5.0f,out_jk,64,0,1);
  MlpArgs ma;
  ma.w0=(const float*)d_in[33]; ma.b0=(const float*)d_in[34];
  ma.w1=(const float*)d_in[35]; ma.b1=(const float*)d_in[36];
  ma.w2=(const float*)d_in[37]; ma.b2=(const float*)d_in[38];
  ma.w3=(const float*)d_in[39]; ma.b3=(const float*)d_in[40];
  ma.w4=(const float*)d_in[41]; ma.b4=(const float*)d_in[42];
  ma.w5=(const float*)d_in[43]; ma.b5=(const float*)d_in[44];
  k_mlp<<<NI_N/256,256,0,stream>>>(out_jk,ma,(float*)d_out,NI_N);
}

// Round 8
// 1479.347 us; speedup vs baseline: 1.0882x; 1.0421x over previous
//
#include <hip/hip_runtime.h>
#include <cmath>

typedef _Float16 f16_t;                                         // IEEE fp16
typedef __attribute__((ext_vector_type(8))) short short8;       // MFMA A/B frag (bit container)
typedef __attribute__((ext_vector_type(8))) _Float16 half8;     // MFMA f16 frag
typedef __attribute__((ext_vector_type(4))) float f32x4;        // MFMA C/D frag
typedef _Float16 h2v __attribute__((ext_vector_type(2)));       // packed f16 pair
typedef _Float16 h8 __attribute__((ext_vector_type(8)));        // 16B f16 vector
typedef float f2 __attribute__((ext_vector_type(2)));           // packed f32 pair

#define NI_N 32768
#define NV_N 131072
#define E_VV 1048576
#define E_VI 524288
#define E_IV 524288
#define NT_N (NV_N+NV_N+NI_N)          // 294912 concatenated nodes (vv|iv|vi)
#define ET_N (E_VV+E_IV+E_VI)          // 2097152 concatenated edges
#define SC_WIN 2                        // scatter windows
#define LOG2E 1.4426950408889634f
#define CHV 192                         // row-chunks per var panel (colres)
#define CHI 64                          // row-chunks per ins panel
#define CHQ 256                         // row-chunks per qkv panel
#define EPAD 68                         // LDS transpose row stride (floats)

__device__ __forceinline__ float gelu_f(float x){ return 0.5f*x*(1.0f+erff(x*0.7071067811865476f)); }

// split f32 into hi/lo f16 (hi+lo carries ~22 bits of mantissa)
__device__ __forceinline__ void splitf16(float v, short& hi, short& lo){
  f16_t h=(f16_t)v;
  hi=__builtin_bit_cast(short,h);
  f16_t l=(f16_t)(v-(float)h);
  lo=__builtin_bit_cast(short,l);
}
__device__ __forceinline__ f32x4 mfma16(short8 a, short8 b, f32x4 c){
  return __builtin_amdgcn_mfma_f32_16x16x32_f16(__builtin_bit_cast(half8,a),__builtin_bit_cast(half8,b),c,0,0,0);
}
__device__ __forceinline__ float fexp2(float x){
#if __has_builtin(__builtin_amdgcn_exp2f)
  return __builtin_amdgcn_exp2f(x);
#else
  return exp2f(x);
#endif
}
__device__ __forceinline__ float ldval(const float* p){ return *p; }
__device__ __forceinline__ float ldval(const f16_t* p){ return (float)*p; }
__device__ __forceinline__ void stval(float* p,float v){ *p=v; }
__device__ __forceinline__ void stval(f16_t* p,float v){ *p=(f16_t)v; }

// ---------------- fused CSR build over 3 concatenated edge types ----------------
__global__ __launch_bounds__(256) void k_hist3(const int* __restrict__ dvv,const int* __restrict__ div_,
    const int* __restrict__ dvi,int* __restrict__ cnt){
  int i=blockIdx.x*256+threadIdx.x;
  if(i<E_VV) atomicAdd(&cnt[dvv[i]],1);
  else if(i<E_VV+E_IV) atomicAdd(&cnt[NV_N+div_[i-E_VV]],1);
  else atomicAdd(&cnt[2*NV_N+dvi[i-E_VV-E_IV]],1);
}
__global__ __launch_bounds__(512) void k_scan1(const int* __restrict__ cnt,int N,int* __restrict__ rp,int* __restrict__ bsum){
  __shared__ int sh[512];
  int i=blockIdx.x*512+threadIdx.x;
  int v=(i<N)?cnt[i]:0;
  sh[threadIdx.x]=v; __syncthreads();
  for(int off=1;off<512;off<<=1){
    int t=(threadIdx.x>=(unsigned)off)?sh[threadIdx.x-off]:0; __syncthreads();
    sh[threadIdx.x]+=t; __syncthreads();
  }
  if(i<N) rp[i]=sh[threadIdx.x]-v;
  if(threadIdx.x==511) bsum[blockIdx.x]=sh[511];
}
__global__ __launch_bounds__(1024) void k_scan2(const int* __restrict__ bsum,int* __restrict__ boff,int nb){
  __shared__ int sh[1024];
  int t=threadIdx.x;
  int v=(t<nb)?bsum[t]:0;
  sh[t]=v; __syncthreads();
  for(int off=1;off<1024;off<<=1){
    int x=(t>=(unsigned)off)?sh[t-off]:0; __syncthreads();
    sh[t]+=x; __syncthreads();
  }
  if(t<nb) boff[t]=sh[t]-v;
  if(t==1023) boff[nb]=sh[1023];
}
__global__ __launch_bounds__(512) void k_scan3(int* __restrict__ rp,const int* __restrict__ boff,int* __restrict__ cur,int N,int nb){
  int i=blockIdx.x*512+threadIdx.x;
  if(i<N){ int v=rp[i]+boff[i>>9]; rp[i]=v; cur[i]=v; }
  if(i==0) rp[N]=boff[nb];
}
// scatter stores PRE-SCALED source row offsets (src*stride) so the edge kernel does no mul
__global__ __launch_bounds__(256) void k_scatter3w(const int* __restrict__ svv,const int* __restrict__ dvv,
    const int* __restrict__ siv,const int* __restrict__ div_,
    const int* __restrict__ svi,const int* __restrict__ dvi,
    int* __restrict__ cur,int* __restrict__ esrc,int dlo,int dhi){
  int i=blockIdx.x*256+threadIdx.x;
  int d,s;
  if(i<E_VV){ d=dvv[i]; if(d<dlo||d>=dhi) return; s=svv[i]*320; }
  else if(i<E_VV+E_IV){ int j=i-E_VV; d=NV_N+div_[j]; if(d<dlo||d>=dhi) return; s=siv[j]*192; }
  else { int j=i-E_VV-E_IV; d=2*NV_N+dvi[j]; if(d<dlo||d>=dhi) return; s=svi[j]*320; }
  int p=atomicAdd(&cur[d],1); esrc[p]=s;
}

// initial cast: f32 inputs -> f16 x buffers
__global__ __launch_bounds__(256) void k_castx(const float* __restrict__ xi_in,const float* __restrict__ xv_in,
    f16_t* __restrict__ xi,f16_t* __restrict__ xv){
  int i=blockIdx.x*256+threadIdx.x;
  if(i<NI_N*64) xi[i]=(f16_t)xi_in[i];
  else { int j=i-NI_N*64; xv[j]=(f16_t)xv_in[j]; }
}

// ---------------- weight folding for ALL 6 layers in one launch ----------------
// Contiguous block layout: q(64) | k(64) | v(64) [| k2 | v2] so the edge kernel
// loads per-head 16B k-rows and v-rows. q columns scaled by LOG2E for exp2 softmax.
struct FoldArgs{
  const float *Wk_i,*Wq_i,*Wv_i,*bk_i,*bq_i,*bv_i;
  const float *Wk_v,*Wq_v,*Wv_v,*bk_v,*bq_v,*bv_v;
  const float *arel_vv,*mrel_vv,*prel_vv,*arel_vi,*mrel_vi,*prel_vi,*arel_iv,*mrel_iv,*prel_iv;
  const float *Wa_i,*Wa_v;
  short *fwh_var,*fwl_var,*fwh_ins,*fwl_ins,*wah_i,*wal_i,*wah_v,*wal_v;
  float *fwb_var,*fwb_ins;
};
__global__ __launch_bounds__(256) void k_fold6(FoldArgs fa){
  int gid=blockIdx.x*256+threadIdx.x;
  if(gid>=6*640*64) return;
  int l=gid/(640*64);
  int rem=gid-l*640*64;
  int r=rem>>6, c=rem&63;
  if(r>=512){
    int ro=r&63;
    const float* W=(r<576)?fa.Wa_i:fa.Wa_v;
    short *sh=((r<576)?fa.wah_i:fa.wah_v)+l*4096, *sl=((r<576)?fa.wal_i:fa.wal_v)+l*4096;
    short h,lo; splitf16(W[l*4096+ro*64+c],h,lo);
    sh[ro*64+c]=h; sl[ro*64+c]=lo;
    return;
  }
  const float *W,*B,*rel=nullptr,*prl=nullptr;
  short *sh,*sl; float *fwb; int orow; bool isq=false;
  if(r<320){
    sh=fa.fwh_var+l*320*64; sl=fa.fwl_var+l*320*64; fwb=fa.fwb_var+l*320; orow=r;
    if(r<64){ W=fa.Wq_v; B=fa.bq_v; isq=true; }
    else if(r<128){ W=fa.Wk_v; B=fa.bk_v; rel=fa.arel_vv; prl=fa.prel_vv; }
    else if(r<192){ W=fa.Wv_v; B=fa.bv_v; rel=fa.mrel_vv; }
    else if(r<256){ W=fa.Wk_v; B=fa.bk_v; rel=fa.arel_vi; prl=fa.prel_vi; }
    else         { W=fa.Wv_v; B=fa.bv_v; rel=fa.mrel_vi; }
  }else{
    int rr=r-320; sh=fa.fwh_ins+l*192*64; sl=fa.fwl_ins+l*192*64; fwb=fa.fwb_ins+l*192; orow=rr;
    if(rr<64){ W=fa.Wq_i; B=fa.bq_i; isq=true; }
    else if(rr<128){ W=fa.Wk_i; B=fa.bk_i; rel=fa.arel_iv; prl=fa.prel_iv; }
    else           { W=fa.Wv_i; B=fa.bv_i; rel=fa.mrel_iv; }
  }
  int d=orow&63;
  float val,bval;
  if(!rel){
    val=W[l*4096+d*64+c]; bval=B[l*64+d];
  }else{
    int h=d>>3, e=d&7;
    float s=prl?prl[l*8+h]*0.3535533905932738f:1.0f;
    float acc=0.f,bacc=0.f;
    #pragma unroll
    for(int dd=0;dd<8;dd++){
      float rv=rel[l*512+h*64+dd*8+e];
      acc += W[l*4096+(h*8+dd)*64+c]*rv;
      bacc+= B[l*64+h*8+dd]*rv;
    }
    val=acc*s; bval=bacc*s;
  }
  if(isq){ val*=LOG2E; bval*=LOG2E; }
  short h2q,lo2; splitf16(val,h2q,lo2);
  sh[orow*64+c]=h2q; sl[orow*64+c]=lo2;
  if(c==0) fwb[orow]=bval;
}

__global__ __launch_bounds__(256) void k_split2(const float* __restrict__ W,int n,short* __restrict__ hi,short* __restrict__ lo){
  int i=blockIdx.x*256+threadIdx.x;
  if(i<n){ short h,l2; splitf16(W[i],h,l2); hi[i]=h; lo[i]=l2; }
}

// ---------------- column-resident GEMM: B frags live in registers, block grid-strides rows ----------------
__device__ __forceinline__ void colres_body(const f16_t* __restrict__ A,int nrb,
    const short* __restrict__ Bh,const short* __restrict__ Bl,
    const float* __restrict__ bias,f16_t* __restrict__ out,int octot,int ocol0,
    int c,int CH,int wave,int lane,int m,int quad,f16_t (*rep)[72])
{
  short8 bhi[4][2], blo[4][2]; float bb[4];
  #pragma unroll
  for(int ot=0;ot<4;ot++){
    size_t o=(size_t)(ocol0+ot*16+m)*64+quad*8;
    bhi[ot][0]=*(const short8*)(Bh+o);    bhi[ot][1]=*(const short8*)(Bh+o+32);
    blo[ot][0]=*(const short8*)(Bl+o);    blo[ot][1]=*(const short8*)(Bl+o+32);
    bb[ot]=bias[ocol0+ot*16+m];
  }
  int rr0=lane>>3, seg=lane&7;
  for(int rb=c;rb<nrb;rb+=CH){
    int row0=rb*64+wave*16;
    const f16_t* ap=A+(size_t)(row0+m)*64+quad*8;
    short8 a0=*(const short8*)(const void*)ap;
    short8 a1=*(const short8*)(const void*)(ap+32);
    f32x4 acc[4];
    #pragma unroll
    for(int ot=0;ot<4;ot++){ f32x4 t={bb[ot],bb[ot],bb[ot],bb[ot]}; acc[ot]=t; }
    #pragma unroll
    for(int ot=0;ot<4;ot++){
      acc[ot]=mfma16(a0,blo[ot][0],acc[ot]);
      acc[ot]=mfma16(a0,bhi[ot][0],acc[ot]);
      acc[ot]=mfma16(a1,blo[ot][1],acc[ot]);
      acc[ot]=mfma16(a1,bhi[ot][1],acc[ot]);
    }
    #pragma unroll
    for(int ot=0;ot<4;ot++)
      #pragma unroll
      for(int r=0;r<4;r++)
        rep[quad*4+r][ot*16+m]=(f16_t)acc[ot][r];
    #pragma unroll
    for(int it=0;it<2;it++){
      int rr=it*8+rr0;
      h8 vals=*(const h8*)&rep[rr][seg*8];
      *(h8*)(out+(size_t)(row0+rr)*octot+ocol0+seg*8)=vals;
    }
  }
}

// fused feature GEMM: blocks [0,5*CHV) var panels, rest ins panels
__global__ __launch_bounds__(256) void k_colres_feat(const f16_t* __restrict__ Av,const f16_t* __restrict__ Ai,
    const short* __restrict__ Bvh,const short* __restrict__ Bvl,const float* __restrict__ biasv,
    const short* __restrict__ Bih,const short* __restrict__ Bil,const float* __restrict__ biasi,
    f16_t* __restrict__ outv,f16_t* __restrict__ outi)
{
  __shared__ f16_t rep[4][16][72];
  const int wave=threadIdx.x>>6, lane=threadIdx.x&63;
  const int m=lane&15, quad=lane>>4;
  int bx=blockIdx.x;
  if(bx<5*CHV){
    int pan=bx/CHV, c=bx%CHV;
    colres_body(Av,NV_N/64,Bvh,Bvl,biasv,outv,320,pan*64,c,CHV,wave,lane,m,quad,rep[wave]);
  }else{
    bx-=5*CHV;
    int pan=bx/CHI, c=bx%CHI;
    colres_body(Ai,NI_N/64,Bih,Bil,biasi,outi,192,pan*64,c,CHI,wave,lane,m,quad,rep[wave]);
  }
}

// generic single-input column-resident GEMM (used for JK qkv)
__global__ __launch_bounds__(256) void k_colres1(const f16_t* __restrict__ A,int nrb,
    const short* __restrict__ Bh,const short* __restrict__ Bl,
    const float* __restrict__ bias,f16_t* __restrict__ out,int octot,int CH)
{
  __shared__ f16_t rep[4][16][72];
  const int wave=threadIdx.x>>6, lane=threadIdx.x&63;
  const int m=lane&15, quad=lane>>4;
  int pan=blockIdx.x/CH, c=blockIdx.x%CH;
  colres_body(A,nrb,Bh,Bl,bias,out,octot,pan*64,c,CH,wave,lane,m,quad,rep[wave]);
}

// ---------------- legacy GEMM body (float A path for osum @ Wo) ----------------
template<typename AT, typename OT>
__device__ __forceinline__ void gemm_body(const AT* __restrict__ A,int row0,
    const short* __restrict__ Bh,const short* __restrict__ Bl,
    const float* __restrict__ bias,float bias_scale,
    OT* __restrict__ out,int octot,int ocol0,int npanels,int m,int quad,int lane,
    f16_t (*rep)[72])
{
  const AT* ap=A+(size_t)(row0+m)*64+quad*8;
  constexpr bool AF16 = (sizeof(AT)==2);
  short8 ahi[2], alo[2];
  if constexpr(AF16){
    #pragma unroll
    for(int kf=0;kf<2;kf++) ahi[kf]=*(const short8*)(const void*)(ap+kf*32);
  }else{
    #pragma unroll
    for(int kf=0;kf<2;kf++){
      short8 th,tl;
      #pragma unroll
      for(int j=0;j<8;j++){ short h,l2; splitf16(ldval(&ap[kf*32+j]),h,l2); th[j]=h; tl[j]=l2; }
      ahi[kf]=th; alo[kf]=tl;
    }
  }
  for(int pan=0;pan<npanels;pan++){
    int colbase=pan*64;
    short8 bhi[4][2], blo[4][2];
    #pragma unroll
    for(int ot=0;ot<4;ot++){
      size_t o=(size_t)(colbase+ot*16+m)*64+quad*8;
      #pragma unroll
      for(int kf=0;kf<2;kf++){
        bhi[ot][kf]=*(const short8*)(Bh+o+kf*32);
        blo[ot][kf]=*(const short8*)(Bl+o+kf*32);
      }
    }
    f32x4 acc[4];
    #pragma unroll
    for(int ot=0;ot<4;ot++){
      float bv=bias[colbase+ot*16+m]*bias_scale;
      acc[ot][0]=bv; acc[ot][1]=bv; acc[ot][2]=bv; acc[ot][3]=bv;
    }
    #pragma unroll
    for(int ot=0;ot<4;ot++){
      #pragma unroll
      for(int kf=0;kf<2;kf++){
        if constexpr(!AF16) acc[ot]=mfma16(alo[kf],bhi[ot][kf],acc[ot]);
        acc[ot]=mfma16(ahi[kf],blo[ot][kf],acc[ot]);
        acc[ot]=mfma16(ahi[kf],bhi[ot][kf],acc[ot]);
      }
    }
    if constexpr(sizeof(OT)==2){
      #pragma unroll
      for(int ot=0;ot<4;ot++)
        #pragma unroll
        for(int r=0;r<4;r++)
          rep[quad*4+r][ot*16+m]=(f16_t)acc[ot][r];
      #pragma unroll
      for(int it=0;it<2;it++){
        int rr=it*8+(lane>>3), seg=lane&7;
        h8 vals=*(const h8*)&rep[rr][seg*8];
        *(h8*)(out+(size_t)(row0+rr)*octot+ocol0+colbase+seg*8)=vals;
      }
    }else{
      #pragma unroll
      for(int ot=0;ot<4;ot++){
        int col=ocol0+colbase+ot*16+m;
        #pragma unroll
        for(int r=0;r<4;r++){
          int row=row0+quad*4+r;
          stval(&out[(size_t)row*octot+col],acc[ot][r]);
        }
      }
    }
  }
}

template<typename AT, typename OT>
__global__ __launch_bounds__(256) void k_gemm64p(const AT* __restrict__ A,int N,
    const short* __restrict__ Bh,const short* __restrict__ Bl,
    const float* __restrict__ bias,float bias_scale,
    OT* __restrict__ out,int octot,int ocol0,int npanels)
{
  __shared__ f16_t rep[4][16][72];
  const int wave=threadIdx.x>>6, lane=threadIdx.x&63;
  const int m=lane&15, quad=lane>>4;
  const int row0=blockIdx.x*64+wave*16;
  if(row0>=N) return;
  gemm_body<AT,OT>(A,row0,Bh,Bl,bias,bias_scale,out,octot,ocol0,npanels,m,quad,lane,rep[wave]);
}

// ---------------- fused per-layer update (instr blocks then var blocks), x/agg f16, LDS-repacked I/O ----------------
__global__ __launch_bounds__(256) void k_update2(const f16_t* __restrict__ agg_i,const f16_t* __restrict__ agg_v,
    const short* __restrict__ wah_i,const short* __restrict__ wal_i,
    const short* __restrict__ wah_v,const short* __restrict__ wal_v,
    const float* __restrict__ ba_i,const float* __restrict__ ba_v,
    const float* __restrict__ skip_i,const float* __restrict__ skip_v,
    f16_t* __restrict__ x_i,f16_t* __restrict__ x_v,
    f16_t* __restrict__ outs,int nbi)
{
  __shared__ f16_t rep[4][16][72];
  const int wave=threadIdx.x>>6, lane=threadIdx.x&63;
  const int m=lane&15, quad=lane>>4;
  const bool isI=(int)blockIdx.x<nbi;
  const int row0=(isI?blockIdx.x:(blockIdx.x-nbi))*64+wave*16;
  const f16_t* agg=isI?agg_i:agg_v;
  const short* Wah=isI?wah_i:wah_v;
  const short* Wal=isI?wal_i:wal_v;
  const float* ba=isI?ba_i:ba_v;
  const float* skip=isI?skip_i:skip_v;
  f16_t* x=isI?x_i:x_v;
  f16_t* oo=isI?outs:nullptr;
  f16_t (*R)[72]=rep[wave];
  short8 bhi[4][2], blo[4][2];
  #pragma unroll
  for(int ot=0;ot<4;ot++){
    size_t o=(size_t)(ot*16+m)*64+quad*8;
    #pragma unroll
    for(int kf=0;kf<2;kf++){
      bhi[ot][kf]=*(const short8*)(Wah+o+kf*32);
      blo[ot][kf]=*(const short8*)(Wal+o+kf*32);
    }
  }
  const f16_t* ap=agg+(size_t)(row0+m)*64+quad*8;
  short8 ahi[2], alo[2];
  #pragma unroll
  for(int kf=0;kf<2;kf++){
    short8 th,tl;
    #pragma unroll
    for(int j=0;j<8;j++){ short h,l2; splitf16(gelu_f((float)ap[kf*32+j]),h,l2); th[j]=h; tl[j]=l2; }
    ahi[kf]=th; alo[kf]=tl;
  }
  // stage x rows into LDS (wide loads)
  int rr0=lane>>3, seg=lane&7;
  h8 x0=*(const h8*)(x+(size_t)(row0+rr0)*64+seg*8);
  h8 x1=*(const h8*)(x+(size_t)(row0+8+rr0)*64+seg*8);
  *(h8*)&R[rr0][seg*8]=x0;
  *(h8*)&R[8+rr0][seg*8]=x1;
  f32x4 acc[4];
  #pragma unroll
  for(int ot=0;ot<4;ot++){
    float bv=ba[ot*16+m];
    acc[ot][0]=bv; acc[ot][1]=bv; acc[ot][2]=bv; acc[ot][3]=bv;
  }
  #pragma unroll
  for(int ot=0;ot<4;ot++){
    #pragma unroll
    for(int kf=0;kf<2;kf++){
      acc[ot]=mfma16(alo[kf],bhi[ot][kf],acc[ot]);
      acc[ot]=mfma16(ahi[kf],blo[ot][kf],acc[ot]);
      acc[ot]=mfma16(ahi[kf],bhi[ot][kf],acc[ot]);
    }
  }
  float s=1.0f/(1.0f+__expf(-skip[0]));
  #pragma unroll
  for(int ot=0;ot<4;ot++){
    int col=ot*16+m;
    #pragma unroll
    for(int r=0;r<4;r++){
      int row=quad*4+r;
      float xn=s*acc[ot][r]+(1.0f-s)*(float)R[row][col];
      R[row][col]=(f16_t)xn;
    }
  }
  h8 o0=*(const h8*)&R[rr0][seg*8];
  h8 o1=*(const h8*)&R[8+rr0][seg*8];
  *(h8*)(x+(size_t)(row0+rr0)*64+seg*8)=o0;
  *(h8*)(x+(size_t)(row0+8+rr0)*64+seg*8)=o1;
  if(oo){
    *(h8*)(oo+(size_t)(row0+rr0)*64+seg*8)=o0;
    *(h8*)(oo+(size_t)(row0+8+rr0)*64+seg*8)=o1;
  }
}

// ---------------- edge attention: lane = (e_slot, head); r5 math + first-trip prefetch ----------------
// esrc holds PRE-SCALED row offsets. Layout q|k|v blocks (v row = k row + 64 elements).
// q pre-scaled by LOG2E -> exp2 softmax. Caller prefetches first es offset AND first k/v rows,
// so both directions' 3-trip chains (rp -> es -> kv) fly concurrently. In-loop es rotates
// one iteration ahead to hide es->kv serialization for deg>8 lists.
__device__ __forceinline__ float dot8(h8 k,h2v q0,h2v q1,h2v q2,h2v q3){
#if __has_builtin(__builtin_amdgcn_fdot2)
  float p=__builtin_amdgcn_fdot2((h2v){k[0],k[1]},q0,0.f,false);
  p=__builtin_amdgcn_fdot2((h2v){k[2],k[3]},q1,p,false);
  p=__builtin_amdgcn_fdot2((h2v){k[4],k[5]},q2,p,false);
  p=__builtin_amdgcn_fdot2((h2v){k[6],k[7]},q3,p,false);
  return p;
#else
  return (float)k[0]*(float)q0[0]+(float)k[1]*(float)q0[1]
        +(float)k[2]*(float)q1[0]+(float)k[3]*(float)q1[1]
        +(float)k[4]*(float)q2[0]+(float)k[5]*(float)q2[1]
        +(float)k[6]*(float)q3[0]+(float)k[7]*(float)q3[1];
#endif
}

__device__ __forceinline__ float edge_body(int b,int e,const int* __restrict__ es,
    const f16_t* __restrict__ sf,int koff,int e_slot,int lane,
    h2v q0,h2v q1,h2v q2,h2v q3,float* __restrict__ L,h8 pk,h8 pv)
{
  if(b>=e) return 0.f;                 // wave-uniform; degree 0 -> 0 (PyG semantics)
  float m=-1e30f, ls=0.f;
  f2 A0={0.f,0.f},A1={0.f,0.f},A2={0.f,0.f},A3={0.f,0.f};
  const int hb=(lane&7)*8;
  // es prefetch for the second batch
  int off=0;
  if(b+8<e){ int ec=b+8+e_slot; ec=ec<e?ec:e-1; off=es[ec]; }
  // ---- iteration 0 from prefetched registers ----
  {
    bool valid=(b+e_slot)<e;
    float p=dot8(pk,q0,q1,q2,q3);
    p=valid?p:-1e30f;
    float mn=fmaxf(m,p);
    float sc=fexp2(m-mn);
    float w=valid?fexp2(p-mn):0.f;
    ls=fmaf(ls,sc,w);
    f2 S={sc,sc},W={w,w};
    A0=A0*S+W*(f2){(float)pv[0],(float)pv[1]};
    A1=A1*S+W*(f2){(float)pv[2],(float)pv[3]};
    A2=A2*S+W*(f2){(float)pv[4],(float)pv[5]};
    A3=A3*S+W*(f2){(float)pv[6],(float)pv[7]};
    m=mn;
  }
  // ---- remaining batches, es rotated one ahead ----
  for(int i=b+8;i<e;i+=8){
    int inext=i+8;
    int offn=0;
    if(inext<e){ int ec=inext+e_slot; ec=ec<e?ec:e-1; offn=es[ec]; }
    const f16_t* kp=sf+(size_t)(unsigned)off+koff+hb;
    h8 kv=*(const h8*)kp;
    h8 vv=*(const h8*)(kp+64);
    bool valid=(i+e_slot)<e;
    float p=dot8(kv,q0,q1,q2,q3);
    p=valid?p:-1e30f;
    float mn=fmaxf(m,p);
    float sc=fexp2(m-mn);
    float w=valid?fexp2(p-mn):0.f;
    ls=fmaf(ls,sc,w);
    f2 S={sc,sc},W={w,w};
    A0=A0*S+W*(f2){(float)vv[0],(float)vv[1]};
    A1=A1*S+W*(f2){(float)vv[2],(float)vv[3]};
    A2=A2*S+W*(f2){(float)vv[4],(float)vv[5]};
    A3=A3*S+W*(f2){(float)vv[6],(float)vv[7]};
    m=mn;
    off=offn;
  }
  // combine across e_slot (lanes xor 8/16/32 share the same head)
  float mall=fmaxf(m,__shfl_xor(m,8));
  mall=fmaxf(mall,__shfl_xor(mall,16));
  mall=fmaxf(mall,__shfl_xor(mall,32));
  float scl=fexp2(m-mall);           // empty lane: exp2(-1e30-finite)=0
  ls*=scl;
  float lsall=ls+__shfl_xor(ls,8);
  lsall+=__shfl_xor(lsall,16);
  lsall+=__shfl_xor(lsall,32);
  f2 S2={scl,scl};
  A0*=S2; A1*=S2; A2*=S2; A3*=S2;
  // LDS transpose: write [e_slot][h*8+d] at EPAD stride, read [e][lane]
  float* wp=L+e_slot*EPAD+hb;
  *(f32x4*)wp=(f32x4){A0[0],A0[1],A1[0],A1[1]};
  *(f32x4*)(wp+4)=(f32x4){A2[0],A2[1],A3[0],A3[1]};
  __asm__ volatile("s_waitcnt lgkmcnt(0)" ::: "memory");
  float r=0.f;
  #pragma unroll
  for(int ee=0;ee<8;ee++) r+=L[ee*EPAD+lane];
  float lsr=__shfl(lsall,lane>>3);   // ls for head (lane>>3) lives at lane (lane>>3)
  return r/(lsr+1e-16f);
}

// fused edge kernel: blocks [0,nbv) var destinations (vv+iv chains prefetched together), rest instr (vi)
__global__ __launch_bounds__(256) void k_edge_all(const int* __restrict__ rp_all,const int* __restrict__ es,
    const f16_t* __restrict__ var_feat,const f16_t* __restrict__ ins_feat,
    f16_t* __restrict__ agg_v,f16_t* __restrict__ agg_i,int nbv)
{
  __shared__ float lds[4][8*EPAD];
  int wave=threadIdx.x>>6, lane=threadIdx.x&63;
  int e_slot=lane>>3, hb=(lane&7)*8;
  float* L=lds[wave];
  if((int)blockIdx.x<nbv){
    int n=blockIdx.x*4+wave;
    // trip 1: both rp reads in flight together
    int b1=__builtin_amdgcn_readfirstlane(rp_all[n]);
    int e1=__builtin_amdgcn_readfirstlane(rp_all[n+1]);
    const int* rp2=rp_all+NV_N;
    int b2=__builtin_amdgcn_readfirstlane(rp2[n]);
    int e2=__builtin_amdgcn_readfirstlane(rp2[n+1]);
    h8 qv=*(const h8*)(var_feat+(size_t)n*320+hb);
    // trip 2: both first es gathers
    int off1=0,off2=0;
    if(b1<e1){ int ec=b1+e_slot; ec=ec<e1?ec:e1-1; off1=es[ec]; }
    if(b2<e2){ int ec=b2+e_slot; ec=ec<e2?ec:e2-1; off2=es[ec]; }
    // trip 3: both first k/v row gathers
    h8 pk1={},pv1={},pk2={},pv2={};
    if(b1<e1){
      const f16_t* p1=var_feat+(size_t)(unsigned)off1+64+hb;
      pk1=*(const h8*)p1; pv1=*(const h8*)(p1+64);
    }
    if(b2<e2){
      const f16_t* p2=ins_feat+(size_t)(unsigned)off2+64+hb;
      pk2=*(const h8*)p2; pv2=*(const h8*)(p2+64);
    }
    h2v q0={qv[0],qv[1]},q1={qv[2],qv[3]},q2={qv[4],qv[5]},q3={qv[6],qv[7]};
    float r1=edge_body(b1,e1,es,var_feat,64,e_slot,lane,q0,q1,q2,q3,L,pk1,pv1);
    float r2=edge_body(b2,e2,es,ins_feat,64,e_slot,lane,q0,q1,q2,q3,L,pk2,pv2);
    agg_v[(size_t)n*64+lane]=(f16_t)(r1+r2);
  }else{
    int n=((int)blockIdx.x-nbv)*4+wave;
    const int* rp=rp_all+2*NV_N;
    int b=__builtin_amdgcn_readfirstlane(rp[n]);
    int e=__builtin_amdgcn_readfirstlane(rp[n+1]);
    h8 qv=*(const h8*)(ins_feat+(size_t)n*192+hb);
    int off0=0;
    if(b<e){ int ec=b+e_slot; ec=ec<e?ec:e-1; off0=es[ec]; }
    h8 pk={},pv={};
    if(b<e){
      const f16_t* p=var_feat+(size_t)(unsigned)off0+192+hb;
      pk=*(const h8*)p; pv=*(const h8*)(p+64);
    }
    h2v q0={qv[0],qv[1]},q1={qv[2],qv[3]},q2={qv[4],qv[5]},q3={qv[6],qv[7]};
    float r=edge_body(b,e,es,var_feat,192,e_slot,lane,q0,q1,q2,q3,L,pk,pv);
    agg_i[(size_t)n*64+lane]=(f16_t)r;
  }
}

// ---------------- jumping-knowledge 5x5 attention, one wave per node
__global__ __launch_bounds__(256) void k_jk(const f16_t* __restrict__ qkv,float* __restrict__ osum,int n_nodes){
  int wave=threadIdx.x>>6, lane=threadIdx.x&63;
  int n=blockIdx.x*4+wave;
  if(n>=n_nodes) return;
  float q[5],k[5],v[5];
  #pragma unroll
  for(int s=0;s<5;s++){
    const f16_t* p=qkv+((size_t)s*n_nodes+n)*192;
    q[s]=(float)p[lane]; k[s]=(float)p[64+lane]; v[s]=(float)p[128+lane];
  }
  float sc[5][5];
  #pragma unroll
  for(int s=0;s<5;s++)
    #pragma unroll
    for(int t=0;t<5;t++){
      float x=q[s]*k[t];
      x+=__shfl_xor(x,1); x+=__shfl_xor(x,2); x+=__shfl_xor(x,4);
      sc[s][t]=x*0.3535533905932738f;
    }
  float os=0.f;
  #pragma unroll
  for(int s=0;s<5;s++){
    float m=sc[s][0];
    #pragma unroll
    for(int t=1;t<5;t++) m=fmaxf(m,sc[s][t]);
    float den=0.f, acc=0.f;
    #pragma unroll
    for(int t=0;t<5;t++){ float e=__expf(sc[s][t]-m); den+=e; acc+=e*v[t]; }
    os+=acc/den;
  }
  osum[(size_t)n*64+lane]=os;
}

// ---------------- MLP head ----------------
struct MlpArgs{ const float *w0,*b0,*w1,*b1,*w2,*b2,*w3,*b3,*w4,*b4,*w5,*b5; };
__global__ __launch_bounds__(256) void k_mlp(const float* __restrict__ in,MlpArgs ma,float* __restrict__ out,int N){
  __shared__ float sw0[2048],sb0[32],sw1[512],sb1[16],sw2[128],sb2[8],sw3[32],sb3[4],sw4[8],sb4[2],sw5[2],sb5[1];
  for(int i=threadIdx.x;i<2048;i+=256) sw0[i]=ma.w0[i];
  for(int i=threadIdx.x;i<512;i+=256)  sw1[i]=ma.w1[i];
  if(threadIdx.x<128) sw2[threadIdx.x]=ma.w2[threadIdx.x];
  if(threadIdx.x<32){ sb0[threadIdx.x]=ma.b0[threadIdx.x]; sw3[threadIdx.x]=ma.w3[threadIdx.x]; }
  if(threadIdx.x<16) sb1[threadIdx.x]=ma.b1[threadIdx.x];
  if(threadIdx.x<8){ sb2[threadIdx.x]=ma.b2[threadIdx.x]; sw4[threadIdx.x]=ma.w4[threadIdx.x]; }
  if(threadIdx.x<4) sb3[threadIdx.x]=ma.b3[threadIdx.x];
  if(threadIdx.x<2){ sb4[threadIdx.x]=ma.b4[threadIdx.x]; sw5[threadIdx.x]=ma.w5[threadIdx.x]; }
  if(threadIdx.x==0) sb5[0]=ma.b5[0];
  __syncthreads();
  int n=blockIdx.x*256+threadIdx.x;
  if(n>=N) return;
  float a[64];
  const f32x4* p4=(const f32x4*)(in+(size_t)n*64);
  #pragma unroll
  for(int j=0;j<16;j++){ f32x4 t=p4[j]; a[4*j]=t[0]; a[4*j+1]=t[1]; a[4*j+2]=t[2]; a[4*j+3]=t[3]; }
  float h1[32];
  #pragma unroll
  for(int o=0;o<32;o++){ float s=sb0[o];
    #pragma unroll
    for(int c=0;c<64;c++) s+=a[c]*sw0[o*64+c];
    h1[o]=gelu_f(s); }
  float h2q[16];
  #pragma unroll
  for(int o=0;o<16;o++){ float s=sb1[o];
    #pragma unroll
    for(int c=0;c<32;c++) s+=h1[c]*sw1[o*32+c];
    h2q[o]=gelu_f(s); }
  float h3[8];
  #pragma unroll
  for(int o=0;o<8;o++){ float s=sb2[o];
    #pragma unroll
    for(int c=0;c<16;c++) s+=h2q[c]*sw2[o*16+c];
    h3[o]=gelu_f(s); }
  float h4[4];
  #pragma unroll
  for(int o=0;o<4;o++){ float s=sb3[o];
    #pragma unroll
    for(int c=0;c<8;c++) s+=h3[c]*sw3[o*8+c];
    h4[o]=gelu_f(s); }
  float h5[2];
  #pragma unroll
  for(int o=0;o<2;o++){ float s=sb4[o];
    #pragma unroll
    for(int c=0;c<4;c++) s+=h4[c]*sw4[o*4+c];
    h5[o]=gelu_f(s); }
  float r=sb5[0]+h5[0]*sw5[0]+h5[1]*sw5[1];
  out[n]=r;
}

// ================= host launcher =================
extern "C" void kernel_launch(void* const* d_in,const int* in_sizes,int n_in,
                              void* d_out,int out_size,void* d_ws,size_t ws_size,
                              hipStream_t stream){
  (void)in_sizes;(void)n_in;(void)out_size;(void)ws_size;
  const float* x_instr=(const float*)d_in[0];
  const float* x_var  =(const float*)d_in[1];
  const float* ba_i=(const float*)d_in[9];
  const float* skip_i=(const float*)d_in[10];
  const float* ba_v=(const float*)d_in[18];
  const float* skip_v=(const float*)d_in[19];
  const float* Wqkv=(const float*)d_in[29];
  const float* bqkv=(const float*)d_in[30];
  const float* Wo=(const float*)d_in[31];
  const float* bo=(const float*)d_in[32];
  const int* src_vv=(const int*)d_in[45];
  const int* dst_vv=(const int*)d_in[46];
  const int* src_vi=(const int*)d_in[47];
  const int* dst_vi=(const int*)d_in[48];
  const int* src_iv=(const int*)d_in[49];
  const int* dst_iv=(const int*)d_in[50];

  char* w=(char*)d_ws;
  auto alloc=[&](size_t b)->char*{ char* p=w; w+=(b+255)&~(size_t)255; return p; };
  // ---- fused CSR arrays (~12 MB) ----
  int* rp_all=(int*)alloc((size_t)(NT_N+1)*4);
  int* cnt_all=(int*)alloc((size_t)NT_N*4);
  int* cur_all=(int*)alloc((size_t)NT_N*4);
  int* bsum =(int*)alloc(640*4);
  int* boff =(int*)alloc(640*4);
  int* esrc_all=(int*)alloc((size_t)ET_N*4);
  // ---- folded + pre-split weights for all 6 layers (~2.5 MB) ----
  short* fwh_var=(short*)alloc((size_t)6*320*64*2);
  short* fwl_var=(short*)alloc((size_t)6*320*64*2);
  float* fwb_var=(float*)alloc((size_t)6*320*4);
  short* fwh_ins=(short*)alloc((size_t)6*192*64*2);
  short* fwl_ins=(short*)alloc((size_t)6*192*64*2);
  float* fwb_ins=(float*)alloc((size_t)6*192*4);
  short* wah_i=(short*)alloc((size_t)6*64*64*2);
  short* wal_i=(short*)alloc((size_t)6*64*64*2);
  short* wah_v=(short*)alloc((size_t)6*64*64*2);
  short* wal_v=(short*)alloc((size_t)6*64*64*2);
  short* qkvh=(short*)alloc(192*64*2);
  short* qkvl=(short*)alloc(192*64*2);
  short* woh=(short*)alloc(64*64*2);
  short* wol=(short*)alloc(64*64*2);
  // ---- persistent across phases: outs (f16, 21 MB) ----
  f16_t* outs=(f16_t*)alloc((size_t)5*NI_N*64*2);
  // ---- arena (140 MB), phase-overlaid ----
  char* arena=alloc((size_t)146800640);
  f16_t*  xv      =(f16_t*)(arena);                                // 16,777,216 B
  f16_t*  xi      =(f16_t*)(arena+16777216);                       //  4,194,304 B
  f16_t*  var_feat=(f16_t*)(arena+20971520);                       // 83,886,080 B (stride 320: q | k_vv | v_vv | k_vi | v_vi)
  f16_t*  ins_feat=(f16_t*)(arena+104857600);                      // 12,582,912 B (stride 192: q | k | v)
  f16_t*  agg_v   =(f16_t*)(arena+117440512);                      // 16,777,216 B
  f16_t*  agg_i   =(f16_t*)(arena+134217728);                      //  4,194,304 B
  // JK phase overlays (xv/xi/var_feat dead by then):
  f16_t*  qkv    =(f16_t*)(arena);                                 // 62,914,560 B
  float*  osum   =(float*)(arena+67108864);                        //  8,388,608 B (inside dead var_feat)
  float*  out_jk =(float*)(arena+75497472);                        //  8,388,608 B (inside dead var_feat)

  // fused CSR build
  hipMemsetAsync(cnt_all,0,(size_t)NT_N*4,stream);
  k_hist3<<<ET_N/256,256,0,stream>>>(dst_vv,dst_iv,dst_vi,cnt_all);
  int nb=NT_N/512;   // 576
  k_scan1<<<nb,512,0,stream>>>(cnt_all,NT_N,rp_all,bsum);
  k_scan2<<<1,1024,0,stream>>>(bsum,boff,nb);
  k_scan3<<<nb,512,0,stream>>>(rp_all,boff,cur_all,NT_N,nb);
  for(int wdx=0;wdx<SC_WIN;wdx++){
    int dlo=wdx*(NT_N/SC_WIN), dhi=(wdx+1)*(NT_N/SC_WIN);
    k_scatter3w<<<ET_N/256,256,0,stream>>>(src_vv,dst_vv,src_iv,dst_iv,src_vi,dst_vi,cur_all,esrc_all,dlo,dhi);
  }

  k_castx<<<(NI_N*64+NV_N*64)/256,256,0,stream>>>(x_instr,x_var,xi,xv);

  // one-time splits for JK weights
  k_split2<<<(192*64+255)/256,256,0,stream>>>(Wqkv,192*64,qkvh,qkvl);
  k_split2<<<(64*64+255)/256,256,0,stream>>>(Wo,64*64,woh,wol);

  FoldArgs fa;
  fa.Wk_i=(const float*)d_in[2]; fa.Wq_i=(const float*)d_in[3]; fa.Wv_i=(const float*)d_in[4];
  fa.bk_i=(const float*)d_in[6]; fa.bq_i=(const float*)d_in[7]; fa.bv_i=(const float*)d_in[8];
  fa.Wk_v=(const float*)d_in[11]; fa.Wq_v=(const float*)d_in[12]; fa.Wv_v=(const float*)d_in[13];
  fa.bk_v=(const float*)d_in[15]; fa.bq_v=(const float*)d_in[16]; fa.bv_v=(const float*)d_in[17];
  fa.arel_vv=(const float*)d_in[20]; fa.mrel_vv=(const float*)d_in[21]; fa.prel_vv=(const float*)d_in[22];
  fa.arel_vi=(const float*)d_in[23]; fa.mrel_vi=(const float*)d_in[24]; fa.prel_vi=(const float*)d_in[25];
  fa.arel_iv=(const float*)d_in[26]; fa.mrel_iv=(const float*)d_in[27]; fa.mrel_iv=(const float*)d_in[27]; fa.prel_iv=(const float*)d_in[28];
  fa.Wa_i=(const float*)d_in[5]; fa.Wa_v=(const float*)d_in[14];
  fa.fwh_var=fwh_var; fa.fwl_var=fwl_var; fa.fwh_ins=fwh_ins; fa.fwl_ins=fwl_ins;
  fa.wah_i=wah_i; fa.wal_i=wal_i; fa.wah_v=wah_v; fa.wal_v=wal_v;
  fa.fwb_var=fwb_var; fa.fwb_ins=fwb_ins;
  k_fold6<<<(6*640*64)/256,256,0,stream>>>(fa);

  for(int l=0;l<6;l++){
    k_colres_feat<<<5*CHV+3*CHI,256,0,stream>>>(xv,xi,
        fwh_var+(size_t)l*320*64,fwl_var+(size_t)l*320*64,fwb_var+l*320,
        fwh_ins+(size_t)l*192*64,fwl_ins+(size_t)l*192*64,fwb_ins+l*192,
        var_feat,ins_feat);
    k_edge_all<<<NV_N/4+NI_N/4,256,0,stream>>>(rp_all,esrc_all,var_feat,ins_feat,agg_v,agg_i,NV_N/4);
    k_update2<<<NI_N/64+NV_N/64,256,0,stream>>>(agg_i,agg_v,
        wah_i+(size_t)l*4096,wal_i+(size_t)l*4096,wah_v+(size_t)l*4096,wal_v+(size_t)l*4096,
        ba_i+l*64,ba_v+l*64,skip_i+l,skip_v+l,xi,xv,
        (l>0)?(outs+(size_t)(l-1)*NI_N*64):nullptr,NI_N/64);
  }

  // jumping knowledge + head
  k_colres1<<<3*CHQ,256,0,stream>>>(outs,5*NI_N/64,qkvh,qkvl,bqkv,qkv,192,CHQ);
  k_jk<<<NI_N/4,256,0,stream>>>(qkv,osum,NI_N);
  k_gemm64p<float,float><<<NI_N/64,256,0,stream>>>(osum,NI_N,woh,wol,bo,5.0f,out_jk,64,0,1);
  MlpArgs ma;
  ma.w0=(const float*)d_in[33]; ma.b0=(const float*)d_in[34];
  ma.w1=(const float*)d_in[35]; ma.b1=(const float*)d_in[36];
  ma.w2=(const float*)d_in[37]; ma.b2=(const float*)d_in[38];
  ma.w3=(const float*)d_in[39]; ma.b3=(const float*)d_in[40];
  ma.w4=(const float*)d_in[41]; ma.b4=(const float*)d_in[42];
  ma.w5=(const float*)d_in[43]; ma.b5=(const float*)d_in[44];
  k_mlp<<<NI_N/256,256,0,stream>>>(out_jk,ma,(float*)d_out,NI_N);
}